// Round 3
// baseline (12488.768 us; speedup 1.0000x reference)
//
#include <hip/hip_runtime.h>
#include <hip/hip_bf16.h>
#include <math.h>

#define B_   32
#define S_   2688
#define D_   128
#define DI_  256
#define DS_  16
#define NROWS (B_*S_)   // 86016

typedef __hip_bfloat16 bf16;

__device__ __forceinline__ float bf2f(bf16 v){ return __bfloat162float(v); }
__device__ __forceinline__ bf16  f2bf(float f){ return __float2bfloat16(f); }
__device__ __forceinline__ float uphalf(unsigned short u){
  union { unsigned int i; float f; } c; c.i = ((unsigned int)u) << 16; return c.f;
}

// ---------------- init: x = concat(feat0, feat1) along seq ----------------
__global__ void k_init_x(const float* __restrict__ f0, const float* __restrict__ f1,
                         float* __restrict__ x){
  int idx = blockIdx.x*256 + threadIdx.x;   // 32*2688*128 = 11,010,048
  if (idx >= B_*S_*D_) return;
  const int per_b = S_*D_;        // 344064
  const int half  = 1344*D_;      // 172032
  int b = idx / per_b;
  int rem = idx - b*per_b;
  x[idx] = (rem < half) ? f0[b*half + rem] : f1[b*half + rem - half];
}

// ---------------- gemm_in: [xi|z] = x(_rev) @ W_in (K=128, 512 cols) -------
__global__ __launch_bounds__(256) void k_gemm_in(const float* __restrict__ x,
      const float* __restrict__ W, bf16* __restrict__ xi, bf16* __restrict__ z, int rev){
  __shared__ __align__(16) float a_sh[32][128];
  const int r0 = blockIdx.x * 32;
  const int b  = r0 / S_;
  const int t0 = r0 - b*S_;
  const int tid = threadIdx.x;
  #pragma unroll
  for (int q=0;q<4;q++){
    int fid = tid + 256*q;          // 0..1023
    int r  = fid >> 5;
    int c4 = fid & 31;
    int t  = t0 + r;
    int rg = b*S_ + (rev ? (S_-1 - t) : t);
    float4 v = *reinterpret_cast<const float4*>(x + (size_t)rg*128 + c4*4);
    *reinterpret_cast<float4*>(&a_sh[r][c4*4]) = v;
  }
  __syncthreads();
  float acc0[32], acc1[32];
  #pragma unroll
  for (int r=0;r<32;r++){ acc0[r]=0.f; acc1[r]=0.f; }
  const int c0 = tid, c1 = tid + 256;
  for (int k4=0;k4<32;k4++){
    int k = k4*4;
    float w00=W[(k+0)*512+c0], w01=W[(k+1)*512+c0], w02=W[(k+2)*512+c0], w03=W[(k+3)*512+c0];
    float w10=W[(k+0)*512+c1], w11=W[(k+1)*512+c1], w12=W[(k+2)*512+c1], w13=W[(k+3)*512+c1];
    #pragma unroll
    for (int r=0;r<32;r++){
      float4 a = *reinterpret_cast<const float4*>(&a_sh[r][k]);
      acc0[r] = fmaf(a.x,w00, fmaf(a.y,w01, fmaf(a.z,w02, fmaf(a.w,w03, acc0[r]))));
      acc1[r] = fmaf(a.x,w10, fmaf(a.y,w11, fmaf(a.z,w12, fmaf(a.w,w13, acc1[r]))));
    }
  }
  #pragma unroll
  for (int r=0;r<32;r++){
    size_t row = (size_t)(r0 + r);
    xi[row*256 + tid] = f2bf(acc0[r]);
    z [row*256 + tid] = f2bf(acc1[r]);
  }
}

// ---------------- conv + silu: xc = silu(dwconv_causal(xi)) ----------------
__global__ void k_conv_silu(const bf16* __restrict__ xi, const float* __restrict__ cw,
                            const float* __restrict__ cb, bf16* __restrict__ xc){
  int idx = blockIdx.x*256 + threadIdx.x;   // NROWS*256
  int d   = idx & 255;
  int row = idx >> 8;
  int t   = row % S_;
  float acc = cb[d];
  #pragma unroll
  for (int j=0;j<4;j++){
    int tj = t - 3 + j;
    if (tj >= 0) acc = fmaf(cw[d*4+j], bf2f(xi[(size_t)(row-3+j)*256 + d]), acc);
  }
  float sig = 1.f/(1.f + __expf(-acc));
  xc[idx] = f2bf(acc*sig);
}

// -------- gemm_x: xdbl = xc@W_x (40 cols) -> BCdt[row][48] (dbl|B|C|pad) ----
__global__ __launch_bounds__(256) void k_gemm_x(const bf16* __restrict__ xc,
      const float* __restrict__ Wx, float* __restrict__ BCdt){
  __shared__ __align__(16) float a_sh[32][256];   // 32 KB
  const int r0 = blockIdx.x*32;
  const int tid = threadIdx.x;
  #pragma unroll
  for (int q=0;q<4;q++){
    int fid = tid + 256*q;          // 0..1023, 8 bf16 each
    int r  = fid >> 5;
    int g8 = fid & 31;
    uint4 raw = *reinterpret_cast<const uint4*>(xc + (size_t)(r0+r)*256 + g8*8);
    float* dst = &a_sh[r][g8*8];
    unsigned int wv[4] = {raw.x, raw.y, raw.z, raw.w};
    #pragma unroll
    for (int p=0;p<4;p++){
      dst[p*2+0] = uphalf((unsigned short)(wv[p] & 0xffffu));
      dst[p*2+1] = uphalf((unsigned short)(wv[p] >> 16));
    }
  }
  __syncthreads();
  const int c  = tid & 63;      // col (0..39 active)
  const int rg = tid >> 6;      // 0..3 -> rows rg*8 .. rg*8+7
  float acc[8];
  #pragma unroll
  for (int i=0;i<8;i++) acc[i]=0.f;
  if (c < 40){
    for (int k4=0;k4<64;k4++){
      int k = k4*4;
      float w0=Wx[(k+0)*40+c], w1=Wx[(k+1)*40+c], w2=Wx[(k+2)*40+c], w3=Wx[(k+3)*40+c];
      #pragma unroll
      for (int rr=0;rr<8;rr++){
        float4 a = *reinterpret_cast<const float4*>(&a_sh[rg*8+rr][k]);
        acc[rr] = fmaf(a.x,w0, fmaf(a.y,w1, fmaf(a.z,w2, fmaf(a.w,w3, acc[rr]))));
      }
    }
    #pragma unroll
    for (int rr=0;rr<8;rr++)
      BCdt[(size_t)(r0+rg*8+rr)*48 + c] = acc[rr];
  }
}

// ---------------- selective scan (16 lanes per (b,d) channel) --------------
// dt computed in-kernel: dt = softplus(sum_j dbl[j]*Wdt[j,d] + b_dt[d])
__global__ __launch_bounds__(256) void k_scan(const bf16* __restrict__ xc,
      const float* __restrict__ BCdt, const bf16* __restrict__ zb,
      const float* __restrict__ Alog, const float* __restrict__ Dpar,
      const float* __restrict__ Wdt, const float* __restrict__ bdt,
      bf16* __restrict__ ym){
  const int tid = threadIdx.x;
  const int n = tid & 15;
  const int b = blockIdx.x >> 4;
  const int d = ((blockIdx.x & 15) << 4) + (tid >> 4);
  const float An   = -__expf(Alog[d*16 + n]);
  const float Dpv  = Dpar[d];
  const float wdtn = Wdt[(n & 7)*256 + d];
  const float bd   = bdt[d];
  float h = 0.f;
  const size_t rowbase = (size_t)b * S_;
  for (int t=0;t<S_;t++){
    size_t row = rowbase + t;
    const float* bc = BCdt + row*48;
    float dblv = bc[n & 7];
    float Bv   = bc[8 + n];
    float Cv   = bc[24 + n];
    float u    = bf2f(xc[row*256 + d]);
    // dt reduce over 8 (lanes 0-7 and 8-15 each hold the full sum)
    float v = dblv * wdtn;
    v += __shfl_xor(v, 1);
    v += __shfl_xor(v, 2);
    v += __shfl_xor(v, 4);
    v += bd;
    float dtv = (v > 20.f) ? v : log1pf(__expf(v));
    float da = __expf(dtv * An);
    h = fmaf(da, h, dtv*u*Bv);
    float p = h * Cv;
    p += __shfl_xor(p, 1);
    p += __shfl_xor(p, 2);
    p += __shfl_xor(p, 4);
    p += __shfl_xor(p, 8);
    if (n == 0){
      float zv = bf2f(zb[row*256 + d]);
      float y = fmaf(u, Dpv, p);
      float sig = 1.f/(1.f + __expf(-zv));
      ym[row*256 + d] = f2bf(y * zv * sig);
    }
  }
}

// ------- gemm_out: dx = ym @ W_out (K=256, 128 cols), fwd/bwd-fold ---------
// rev=0: dx[row]  = 0.5*acc   (bf16)
// rev=1: dx[rrev] = bf2f(old) + 0.5*acc  (combines both directions)
__global__ __launch_bounds__(256) void k_gemm_out(const bf16* __restrict__ ym,
      const float* __restrict__ W, bf16* __restrict__ dx, int rev){
  __shared__ __align__(16) float a_sh[32][256];
  const int r0 = blockIdx.x*32;
  const int b  = r0 / S_;
  const int t0 = r0 - b*S_;
  const int tid = threadIdx.x;
  #pragma unroll
  for (int q=0;q<4;q++){
    int fid = tid + 256*q;
    int r  = fid >> 5;
    int g8 = fid & 31;
    uint4 raw = *reinterpret_cast<const uint4*>(ym + (size_t)(r0+r)*256 + g8*8);
    float* dst = &a_sh[r][g8*8];
    unsigned int wv[4] = {raw.x, raw.y, raw.z, raw.w};
    #pragma unroll
    for (int p=0;p<4;p++){
      dst[p*2+0] = uphalf((unsigned short)(wv[p] & 0xffffu));
      dst[p*2+1] = uphalf((unsigned short)(wv[p] >> 16));
    }
  }
  __syncthreads();
  const int c     = tid & 127;
  const int rbase = (tid >> 7) * 16;
  float acc[16];
  #pragma unroll
  for (int i=0;i<16;i++) acc[i]=0.f;
  for (int k4=0;k4<64;k4++){
    int k = k4*4;
    float w0=W[(k+0)*128+c], w1=W[(k+1)*128+c], w2=W[(k+2)*128+c], w3=W[(k+3)*128+c];
    #pragma unroll
    for (int rr=0;rr<16;rr++){
      float4 a = *reinterpret_cast<const float4*>(&a_sh[rbase+rr][k]);
      acc[rr] = fmaf(a.x,w0, fmaf(a.y,w1, fmaf(a.z,w2, fmaf(a.w,w3, acc[rr]))));
    }
  }
  #pragma unroll
  for (int rr=0;rr<16;rr++){
    int t = t0 + rbase + rr;
    size_t drow = (size_t)b*S_ + (rev ? (S_-1 - t) : t);
    if (rev){
      float old = bf2f(dx[drow*128 + c]);
      dx[drow*128 + c] = f2bf(old + 0.5f*acc[rr]);
    } else {
      dx[drow*128 + c] = f2bf(0.5f*acc[rr]);
    }
  }
}

// ------------- combine + layernorm + residual: x += LN(dx) -----------------
__global__ __launch_bounds__(256) void k_combine_ln(const bf16* __restrict__ dx,
      const float* __restrict__ lnw, const float* __restrict__ lnb,
      float* __restrict__ x){
  const int tid  = threadIdx.x;
  const int lane = tid & 63;
  const int row  = blockIdx.x*4 + (tid >> 6);
  const int c0 = lane, c1 = lane + 64;
  float v0 = bf2f(dx[(size_t)row*128 + c0]);
  float v1 = bf2f(dx[(size_t)row*128 + c1]);
  float s = v0 + v1;
  #pragma unroll
  for (int m=1;m<64;m<<=1) s += __shfl_xor(s, m);
  float mu = s * (1.f/128.f);
  float d0 = v0 - mu, d1 = v1 - mu;
  float q = d0*d0 + d1*d1;
  #pragma unroll
  for (int m=1;m<64;m<<=1) q += __shfl_xor(q, m);
  float rs = rsqrtf(q*(1.f/128.f) + 1e-5f);
  x[(size_t)row*128 + c0] += d0*rs*lnw[c0] + lnb[c0];
  x[(size_t)row*128 + c1] += d1*rs*lnw[c1] + lnb[c1];
}

// ---------------- pyramid gather ----------------
__global__ void k_pyramid(const float* __restrict__ x, float* __restrict__ out){
  int idx = blockIdx.x*256 + threadIdx.x;   // 2*32*128*32*32 = 8,388,608
  int j = idx & 31;
  int i = (idx >> 5) & 31;
  int c = (idx >> 10) & 127;
  int m = (idx >> 17) & 31;
  int o = idx >> 22;
  int base = o*1344;
  size_t xm = ((size_t)m * S_ + base) * 128 + c;
  float v = x[xm + (size_t)(320 + i*32 + j)*128]
          + x[xm + (size_t)(64 + (i>>1)*16 + (j>>1))*128]
          + x[xm + (size_t)((i>>2)*8 + (j>>2))*128];
  out[idx] = v;
}

extern "C" void kernel_launch(void* const* d_in, const int* in_sizes, int n_in,
                              void* d_out, int out_size, void* d_ws, size_t ws_size,
                              hipStream_t stream){
  const float* f0   = (const float*)d_in[0];
  const float* f1   = (const float*)d_in[1];
  const float* W_in = (const float*)d_in[2];
  const float* cw   = (const float*)d_in[3];
  const float* cb   = (const float*)d_in[4];
  const float* Wx   = (const float*)d_in[5];
  const float* Wdt  = (const float*)d_in[6];
  const float* bdt  = (const float*)d_in[7];
  const float* Alog = (const float*)d_in[8];
  const float* Dpar = (const float*)d_in[9];
  const float* Wout = (const float*)d_in[10];
  const float* lnw  = (const float*)d_in[11];
  const float* lnb  = (const float*)d_in[12];

  // workspace layout (bytes):
  //   x    fp32  [0,            44,040,192)
  //   xi   bf16  [44,040,192,   88,080,384)   (reused as ym after conv)
  //   z    bf16  [88,080,384,  132,120,576)
  //   xc   bf16  [132,120,576, 176,160,768)
  //   BCdt fp32  [176,160,768, 192,675,840)   rows*48
  //   dx   bf16  [192,675,840, 214,695,936)
  const size_t NEEDED = 214695936;
  if (ws_size < NEEDED) return;   // diagnostic guard: clean absmax fail, no fault

  char* ws = (char*)d_ws;
  float* x    = (float*)(ws + 0);
  bf16*  xi   = (bf16*) (ws + 44040192);
  bf16*  z    = (bf16*) (ws + 88080384);
  bf16*  xc   = (bf16*) (ws + 132120576);
  float* BCdt = (float*)(ws + 176160768);
  bf16*  dx   = (bf16*) (ws + 192675840);

  k_init_x<<<43008,256,0,stream>>>(f0, f1, x);

  for (int l=0;l<2;l++){
    for (int r=0;r<2;r++){
      int lr = l*2 + r;
      k_gemm_in  <<<2688,256,0,stream>>>(x, W_in + (size_t)lr*128*512, xi, z, r);
      k_conv_silu<<<86016,256,0,stream>>>(xi, cw + lr*256*4, cb + lr*256, xc);
      k_gemm_x   <<<2688,256,0,stream>>>(xc, Wx + (size_t)lr*256*40, BCdt);
      k_scan     <<<512,256,0,stream>>>(xc, BCdt, z,
                                        Alog + (size_t)lr*256*16, Dpar + lr*256,
                                        Wdt + (size_t)lr*8*256, bdt + lr*256, xi);
      k_gemm_out <<<2688,256,0,stream>>>(xi, Wout + (size_t)lr*256*128, dx, r);
    }
    k_combine_ln<<<21504,256,0,stream>>>(dx, lnw + l*128, lnb + l*128, x);
  }

  k_pyramid<<<32768,256,0,stream>>>(x, (float*)d_out);
}

// Round 4
// 4795.211 us; speedup vs baseline: 2.6044x; 2.6044x over previous
//
#include <hip/hip_runtime.h>
#include <hip/hip_bf16.h>
#include <math.h>

#define B_   32
#define S_   2688
#define D_   128
#define DI_  256
#define DS_  16
#define NROWS (B_*S_)   // 86016

typedef __hip_bfloat16 bf16;

__device__ __forceinline__ float bf2f(bf16 v){ return __bfloat162float(v); }
__device__ __forceinline__ bf16  f2bf(float f){ return __float2bfloat16(f); }
__device__ __forceinline__ float uphalf(unsigned short u){
  union { unsigned int i; float f; } c; c.i = ((unsigned int)u) << 16; return c.f;
}

// ---------------- init: x = concat(feat0, feat1) along seq ----------------
__global__ void k_init_x(const float* __restrict__ f0, const float* __restrict__ f1,
                         float* __restrict__ x){
  int idx = blockIdx.x*256 + threadIdx.x;   // 32*2688*128 = 11,010,048
  if (idx >= B_*S_*D_) return;
  const int per_b = S_*D_;        // 344064
  const int half  = 1344*D_;      // 172032
  int b = idx / per_b;
  int rem = idx - b*per_b;
  x[idx] = (rem < half) ? f0[b*half + rem] : f1[b*half + rem - half];
}

// ---------------- gemm_in: [xi|z] = x(_rev) @ W_in (K=128, 512 cols) -------
__global__ __launch_bounds__(256) void k_gemm_in(const float* __restrict__ x,
      const float* __restrict__ W, bf16* __restrict__ xi, bf16* __restrict__ z, int rev){
  __shared__ __align__(16) float a_sh[32][128];
  const int r0 = blockIdx.x * 32;
  const int b  = r0 / S_;
  const int t0 = r0 - b*S_;
  const int tid = threadIdx.x;
  #pragma unroll
  for (int q=0;q<4;q++){
    int fid = tid + 256*q;          // 0..1023
    int r  = fid >> 5;
    int c4 = fid & 31;
    int t  = t0 + r;
    int rg = b*S_ + (rev ? (S_-1 - t) : t);
    float4 v = *reinterpret_cast<const float4*>(x + (size_t)rg*128 + c4*4);
    *reinterpret_cast<float4*>(&a_sh[r][c4*4]) = v;
  }
  __syncthreads();
  float acc0[32], acc1[32];
  #pragma unroll
  for (int r=0;r<32;r++){ acc0[r]=0.f; acc1[r]=0.f; }
  const int c0 = tid, c1 = tid + 256;
  for (int k4=0;k4<32;k4++){
    int k = k4*4;
    float w00=W[(k+0)*512+c0], w01=W[(k+1)*512+c0], w02=W[(k+2)*512+c0], w03=W[(k+3)*512+c0];
    float w10=W[(k+0)*512+c1], w11=W[(k+1)*512+c1], w12=W[(k+2)*512+c1], w13=W[(k+3)*512+c1];
    #pragma unroll
    for (int r=0;r<32;r++){
      float4 a = *reinterpret_cast<const float4*>(&a_sh[r][k]);
      acc0[r] = fmaf(a.x,w00, fmaf(a.y,w01, fmaf(a.z,w02, fmaf(a.w,w03, acc0[r]))));
      acc1[r] = fmaf(a.x,w10, fmaf(a.y,w11, fmaf(a.z,w12, fmaf(a.w,w13, acc1[r]))));
    }
  }
  #pragma unroll
  for (int r=0;r<32;r++){
    size_t row = (size_t)(r0 + r);
    xi[row*256 + tid] = f2bf(acc0[r]);
    z [row*256 + tid] = f2bf(acc1[r]);
  }
}

// ---------------- conv + silu: xc = silu(dwconv_causal(xi)) ----------------
__global__ void k_conv_silu(const bf16* __restrict__ xi, const float* __restrict__ cw,
                            const float* __restrict__ cb, bf16* __restrict__ xc){
  int idx = blockIdx.x*256 + threadIdx.x;   // NROWS*256
  int d   = idx & 255;
  int row = idx >> 8;
  int t   = row % S_;
  float acc = cb[d];
  #pragma unroll
  for (int j=0;j<4;j++){
    int tj = t - 3 + j;
    if (tj >= 0) acc = fmaf(cw[d*4+j], bf2f(xi[(size_t)(row-3+j)*256 + d]), acc);
  }
  float sig = 1.f/(1.f + __expf(-acc));
  xc[idx] = f2bf(acc*sig);
}

// -- gemm_x+dt: xdbl = xc@W_x; BC[row][32]=B|C fp32; dtT[d][row]=softplus bf16
__global__ __launch_bounds__(256) void k_gemm_x_dt(const bf16* __restrict__ xc,
      const float* __restrict__ Wx, const float* __restrict__ Wdt, const float* __restrict__ bdt,
      float* __restrict__ BC, bf16* __restrict__ dtT){
  __shared__ __align__(16) float a_sh[32][256];   // 32 KB
  __shared__ float s_dbl[32][8];
  const int r0 = blockIdx.x*32;
  const int tid = threadIdx.x;
  #pragma unroll
  for (int q=0;q<4;q++){
    int fid = tid + 256*q;          // 0..1023, 8 bf16 each
    int r  = fid >> 5;
    int g8 = fid & 31;
    uint4 raw = *reinterpret_cast<const uint4*>(xc + (size_t)(r0+r)*256 + g8*8);
    float* dst = &a_sh[r][g8*8];
    unsigned int wv[4] = {raw.x, raw.y, raw.z, raw.w};
    #pragma unroll
    for (int p=0;p<4;p++){
      dst[p*2+0] = uphalf((unsigned short)(wv[p] & 0xffffu));
      dst[p*2+1] = uphalf((unsigned short)(wv[p] >> 16));
    }
  }
  __syncthreads();
  const int c  = tid & 63;      // col (0..39 active)
  const int rg = tid >> 6;      // 0..3 -> rows rg*8 .. rg*8+7
  float acc[8];
  #pragma unroll
  for (int i=0;i<8;i++) acc[i]=0.f;
  if (c < 40){
    for (int k4=0;k4<64;k4++){
      int k = k4*4;
      float w0=Wx[(k+0)*40+c], w1=Wx[(k+1)*40+c], w2=Wx[(k+2)*40+c], w3=Wx[(k+3)*40+c];
      #pragma unroll
      for (int rr=0;rr<8;rr++){
        float4 a = *reinterpret_cast<const float4*>(&a_sh[rg*8+rr][k]);
        acc[rr] = fmaf(a.x,w0, fmaf(a.y,w1, fmaf(a.z,w2, fmaf(a.w,w3, acc[rr]))));
      }
    }
  }
  if (c < 8){
    #pragma unroll
    for (int rr=0;rr<8;rr++) s_dbl[rg*8+rr][c] = acc[rr];
  } else if (c < 40){
    #pragma unroll
    for (int rr=0;rr<8;rr++) BC[(size_t)(r0+rg*8+rr)*32 + (c-8)] = acc[rr];
  }
  __syncthreads();
  // dt phase: thread owns channel d = tid; rows r0..r0+31
  float wdt[8];
  #pragma unroll
  for (int j=0;j<8;j++) wdt[j] = Wdt[j*256 + tid];
  float bd = bdt[tid];
  unsigned short tmp[32];
  #pragma unroll
  for (int r=0;r<32;r++){
    float v = bd;
    #pragma unroll
    for (int j=0;j<8;j++) v = fmaf(s_dbl[r][j], wdt[j], v);
    float sp = (v > 20.f) ? v : log1pf(__expf(v));
    tmp[r] = __hip_bfloat16_raw(f2bf(sp)).x;
  }
  // 32 contiguous bf16 = 64 B per thread, 16B-aligned
  unsigned short* dst = (unsigned short*)dtT + (size_t)tid*NROWS + r0;
  #pragma unroll
  for (int q=0;q<4;q++){
    uint4 pack;
    unsigned int* w = (unsigned int*)&pack;
    #pragma unroll
    for (int p=0;p<4;p++)
      w[p] = (unsigned int)tmp[q*8+p*2] | ((unsigned int)tmp[q*8+p*2+1] << 16);
    *reinterpret_cast<uint4*>(dst + q*8) = pack;
  }
}

// ---------------- selective scan (16 lanes per (b,d) channel) --------------
// per-step critical path is ONE fmaf; everything else h-independent.
__global__ __launch_bounds__(256) void k_scan(const bf16* __restrict__ xc,
      const bf16* __restrict__ dtT, const float* __restrict__ BC, const bf16* __restrict__ zb,
      const float* __restrict__ Alog, const float* __restrict__ Dpar,
      bf16* __restrict__ ym){
  const int tid = threadIdx.x;
  const int n = tid & 15;
  const int b = blockIdx.x >> 4;
  const int d = ((blockIdx.x & 15) << 4) + (tid >> 4);
  const float An  = -__expf(Alog[d*16 + n]);
  const float Dpv = Dpar[d];
  float h = 0.f;
  const size_t rowbase = (size_t)b * S_;
  const bf16* dtp = dtT + (size_t)d*NROWS + rowbase;
  for (int t0=0;t0<S_;t0+=4){
    ushort4 dtraw = *reinterpret_cast<const ushort4*>(dtp + t0);
    float dtv[4] = {uphalf(dtraw.x), uphalf(dtraw.y), uphalf(dtraw.z), uphalf(dtraw.w)};
    float u[4], Bv[4], Cv[4];
    #pragma unroll
    for (int k=0;k<4;k++){
      size_t row = rowbase + t0 + k;
      u[k]  = bf2f(xc[row*256 + d]);
      Bv[k] = BC[row*32 + n];
      Cv[k] = BC[row*32 + 16 + n];
    }
    float da[4], inp[4], p[4];
    #pragma unroll
    for (int k=0;k<4;k++){
      da[k]  = __expf(dtv[k]*An);
      inp[k] = dtv[k]*u[k]*Bv[k];
    }
    #pragma unroll
    for (int k=0;k<4;k++){
      h = fmaf(da[k], h, inp[k]);
      p[k] = h * Cv[k];
    }
    #pragma unroll
    for (int k=0;k<4;k++){
      p[k] += __shfl_xor(p[k], 1);
      p[k] += __shfl_xor(p[k], 2);
      p[k] += __shfl_xor(p[k], 4);
      p[k] += __shfl_xor(p[k], 8);
    }
    if (n == 0){
      #pragma unroll
      for (int k=0;k<4;k++){
        size_t row = rowbase + t0 + k;
        float zv = bf2f(zb[row*256 + d]);
        float y = fmaf(u[k], Dpv, p[k]);
        float sig = 1.f/(1.f + __expf(-zv));
        ym[row*256 + d] = f2bf(y * zv * sig);
      }
    }
  }
}

// ------- gemm_out: dx = ym @ W_out (K=256, 128 cols), fwd/bwd-fold ---------
// rev=0: dx[row]  = 0.5*acc   (bf16)
// rev=1: dx[rrev] = bf2f(old) + 0.5*acc  (combines both directions)
__global__ __launch_bounds__(256) void k_gemm_out(const bf16* __restrict__ ym,
      const float* __restrict__ W, bf16* __restrict__ dx, int rev){
  __shared__ __align__(16) float a_sh[32][256];
  const int r0 = blockIdx.x*32;
  const int b  = r0 / S_;
  const int t0 = r0 - b*S_;
  const int tid = threadIdx.x;
  #pragma unroll
  for (int q=0;q<4;q++){
    int fid = tid + 256*q;
    int r  = fid >> 5;
    int g8 = fid & 31;
    uint4 raw = *reinterpret_cast<const uint4*>(ym + (size_t)(r0+r)*256 + g8*8);
    float* dst = &a_sh[r][g8*8];
    unsigned int wv[4] = {raw.x, raw.y, raw.z, raw.w};
    #pragma unroll
    for (int p=0;p<4;p++){
      dst[p*2+0] = uphalf((unsigned short)(wv[p] & 0xffffu));
      dst[p*2+1] = uphalf((unsigned short)(wv[p] >> 16));
    }
  }
  __syncthreads();
  const int c     = tid & 127;
  const int rbase = (tid >> 7) * 16;
  float acc[16];
  #pragma unroll
  for (int i=0;i<16;i++) acc[i]=0.f;
  for (int k4=0;k4<64;k4++){
    int k = k4*4;
    float w0=W[(k+0)*128+c], w1=W[(k+1)*128+c], w2=W[(k+2)*128+c], w3=W[(k+3)*128+c];
    #pragma unroll
    for (int rr=0;rr<16;rr++){
      float4 a = *reinterpret_cast<const float4*>(&a_sh[rbase+rr][k]);
      acc[rr] = fmaf(a.x,w0, fmaf(a.y,w1, fmaf(a.z,w2, fmaf(a.w,w3, acc[rr]))));
    }
  }
  #pragma unroll
  for (int rr=0;rr<16;rr++){
    int t = t0 + rbase + rr;
    size_t drow = (size_t)b*S_ + (rev ? (S_-1 - t) : t);
    if (rev){
      float old = bf2f(dx[drow*128 + c]);
      dx[drow*128 + c] = f2bf(old + 0.5f*acc[rr]);
    } else {
      dx[drow*128 + c] = f2bf(0.5f*acc[rr]);
    }
  }
}

// ------------- combine + layernorm + residual: x += LN(dx) -----------------
__global__ __launch_bounds__(256) void k_combine_ln(const bf16* __restrict__ dx,
      const float* __restrict__ lnw, const float* __restrict__ lnb,
      float* __restrict__ x){
  const int tid  = threadIdx.x;
  const int lane = tid & 63;
  const int row  = blockIdx.x*4 + (tid >> 6);
  const int c0 = lane, c1 = lane + 64;
  float v0 = bf2f(dx[(size_t)row*128 + c0]);
  float v1 = bf2f(dx[(size_t)row*128 + c1]);
  float s = v0 + v1;
  #pragma unroll
  for (int m=1;m<64;m<<=1) s += __shfl_xor(s, m);
  float mu = s * (1.f/128.f);
  float d0 = v0 - mu, d1 = v1 - mu;
  float q = d0*d0 + d1*d1;
  #pragma unroll
  for (int m=1;m<64;m<<=1) q += __shfl_xor(q, m);
  float rs = rsqrtf(q*(1.f/128.f) + 1e-5f);
  x[(size_t)row*128 + c0] += d0*rs*lnw[c0] + lnb[c0];
  x[(size_t)row*128 + c1] += d1*rs*lnw[c1] + lnb[c1];
}

// ---------------- pyramid gather ----------------
__global__ void k_pyramid(const float* __restrict__ x, float* __restrict__ out){
  int idx = blockIdx.x*256 + threadIdx.x;   // 2*32*128*32*32 = 8,388,608
  int j = idx & 31;
  int i = (idx >> 5) & 31;
  int c = (idx >> 10) & 127;
  int m = (idx >> 17) & 31;
  int o = idx >> 22;
  int base = o*1344;
  size_t xm = ((size_t)m * S_ + base) * 128 + c;
  float v = x[xm + (size_t)(320 + i*32 + j)*128]
          + x[xm + (size_t)(64 + (i>>1)*16 + (j>>1))*128]
          + x[xm + (size_t)((i>>2)*8 + (j>>2))*128];
  out[idx] = v;
}

extern "C" void kernel_launch(void* const* d_in, const int* in_sizes, int n_in,
                              void* d_out, int out_size, void* d_ws, size_t ws_size,
                              hipStream_t stream){
  const float* f0   = (const float*)d_in[0];
  const float* f1   = (const float*)d_in[1];
  const float* W_in = (const float*)d_in[2];
  const float* cw   = (const float*)d_in[3];
  const float* cb   = (const float*)d_in[4];
  const float* Wx   = (const float*)d_in[5];
  const float* Wdt  = (const float*)d_in[6];
  const float* bdt  = (const float*)d_in[7];
  const float* Alog = (const float*)d_in[8];
  const float* Dpar = (const float*)d_in[9];
  const float* Wout = (const float*)d_in[10];
  const float* lnw  = (const float*)d_in[11];
  const float* lnb  = (const float*)d_in[12];

  // workspace layout (bytes):
  //   x    fp32  [0,            44,040,192)
  //   xi   bf16  [44,040,192,   88,080,384)   (reused as dtT[d][row] after conv)
  //   z    bf16  [88,080,384,  132,120,576)
  //   xc   bf16  [132,120,576, 176,160,768)   (reused as ym by scan, in place)
  //   BC   fp32  [176,160,768, 187,170,816)   rows*32 (B|C)
  //   dx   bf16  [192,675,840, 214,695,936)
  const size_t NEEDED = 214695936;
  if (ws_size < NEEDED) return;   // diagnostic guard: clean absmax fail, no fault

  char* ws = (char*)d_ws;
  float* x    = (float*)(ws + 0);
  bf16*  xi   = (bf16*) (ws + 44040192);
  bf16*  dtT  = (bf16*) (ws + 44040192);
  bf16*  z    = (bf16*) (ws + 88080384);
  bf16*  xc   = (bf16*) (ws + 132120576);
  float* BC   = (float*)(ws + 176160768);
  bf16*  dx   = (bf16*) (ws + 192675840);

  k_init_x<<<43008,256,0,stream>>>(f0, f1, x);

  for (int l=0;l<2;l++){
    for (int r=0;r<2;r++){
      int lr = l*2 + r;
      k_gemm_in  <<<2688,256,0,stream>>>(x, W_in + (size_t)lr*128*512, xi, z, r);
      k_conv_silu<<<86016,256,0,stream>>>(xi, cw + lr*256*4, cb + lr*256, xc);
      k_gemm_x_dt<<<2688,256,0,stream>>>(xc, Wx + (size_t)lr*256*40,
                                         Wdt + (size_t)lr*8*256, bdt + lr*256, BC, dtT);
      k_scan     <<<512,256,0,stream>>>(xc, dtT, BC, z,
                                        Alog + (size_t)lr*256*16, Dpar + lr*256, xc);
      k_gemm_out <<<2688,256,0,stream>>>(xc, Wout + (size_t)lr*256*128, dx, r);
    }
    k_combine_ln<<<21504,256,0,stream>>>(dx, lnw + l*128, lnb + l*128, x);
  }

  k_pyramid<<<32768,256,0,stream>>>(x, (float*)d_out);
}

// Round 5
// 2966.444 us; speedup vs baseline: 4.2100x; 1.6165x over previous
//
#include <hip/hip_runtime.h>
#include <hip/hip_bf16.h>
#include <math.h>

#define B_   32
#define S_   2688
#define D_   128
#define DI_  256
#define DS_  16
#define NROWS (B_*S_)   // 86016

typedef __hip_bfloat16 bf16;

__device__ __forceinline__ float bf2f(bf16 v){ return __bfloat162float(v); }
__device__ __forceinline__ bf16  f2bf(float f){ return __float2bfloat16(f); }
__device__ __forceinline__ float uphalf(unsigned short u){
  union { unsigned int i; float f; } c; c.i = ((unsigned int)u) << 16; return c.f;
}

// ---------------- init: x = concat(feat0, feat1) along seq ----------------
__global__ void k_init_x(const float* __restrict__ f0, const float* __restrict__ f1,
                         float* __restrict__ x){
  int idx = blockIdx.x*256 + threadIdx.x;   // 32*2688*128 = 11,010,048
  if (idx >= B_*S_*D_) return;
  const int per_b = S_*D_;        // 344064
  const int half  = 1344*D_;      // 172032
  int b = idx / per_b;
  int rem = idx - b*per_b;
  x[idx] = (rem < half) ? f0[b*half + rem] : f1[b*half + rem - half];
}

// ---------------- gemm_in: [xi|z] = x(_rev) @ W_in (K=128, 512 cols) -------
__global__ __launch_bounds__(256) void k_gemm_in(const float* __restrict__ x,
      const float* __restrict__ W, bf16* __restrict__ xi, bf16* __restrict__ z, int rev){
  __shared__ __align__(16) float a_sh[32][128];
  const int r0 = blockIdx.x * 32;
  const int b  = r0 / S_;
  const int t0 = r0 - b*S_;
  const int tid = threadIdx.x;
  #pragma unroll
  for (int q=0;q<4;q++){
    int fid = tid + 256*q;          // 0..1023
    int r  = fid >> 5;
    int c4 = fid & 31;
    int t  = t0 + r;
    int rg = b*S_ + (rev ? (S_-1 - t) : t);
    float4 v = *reinterpret_cast<const float4*>(x + (size_t)rg*128 + c4*4);
    *reinterpret_cast<float4*>(&a_sh[r][c4*4]) = v;
  }
  __syncthreads();
  float acc0[32], acc1[32];
  #pragma unroll
  for (int r=0;r<32;r++){ acc0[r]=0.f; acc1[r]=0.f; }
  const int c0 = tid, c1 = tid + 256;
  for (int k4=0;k4<32;k4++){
    int k = k4*4;
    float w00=W[(k+0)*512+c0], w01=W[(k+1)*512+c0], w02=W[(k+2)*512+c0], w03=W[(k+3)*512+c0];
    float w10=W[(k+0)*512+c1], w11=W[(k+1)*512+c1], w12=W[(k+2)*512+c1], w13=W[(k+3)*512+c1];
    #pragma unroll
    for (int r=0;r<32;r++){
      float4 a = *reinterpret_cast<const float4*>(&a_sh[r][k]);
      acc0[r] = fmaf(a.x,w00, fmaf(a.y,w01, fmaf(a.z,w02, fmaf(a.w,w03, acc0[r]))));
      acc1[r] = fmaf(a.x,w10, fmaf(a.y,w11, fmaf(a.z,w12, fmaf(a.w,w13, acc1[r]))));
    }
  }
  #pragma unroll
  for (int r=0;r<32;r++){
    size_t row = (size_t)(r0 + r);
    xi[row*256 + tid] = f2bf(acc0[r]);
    z [row*256 + tid] = f2bf(acc1[r]);
  }
}

// ---------------- conv + silu: xc = silu(dwconv_causal(xi)) ----------------
__global__ void k_conv_silu(const bf16* __restrict__ xi, const float* __restrict__ cw,
                            const float* __restrict__ cb, bf16* __restrict__ xc){
  int idx = blockIdx.x*256 + threadIdx.x;   // NROWS*256
  int d   = idx & 255;
  int row = idx >> 8;
  int t   = row % S_;
  float acc = cb[d];
  #pragma unroll
  for (int j=0;j<4;j++){
    int tj = t - 3 + j;
    if (tj >= 0) acc = fmaf(cw[d*4+j], bf2f(xi[(size_t)(row-3+j)*256 + d]), acc);
  }
  float sig = 1.f/(1.f + __expf(-acc));
  xc[idx] = f2bf(acc*sig);
}

// -- gemm_x+dt: xdbl = xc@W_x; BC[row][32]=B|C fp32; dtb[row][d]=softplus bf16
__global__ __launch_bounds__(256) void k_gemm_x_dt(const bf16* __restrict__ xc,
      const float* __restrict__ Wx, const float* __restrict__ Wdt, const float* __restrict__ bdt,
      float* __restrict__ BC, bf16* __restrict__ dtb){
  __shared__ __align__(16) float a_sh[32][256];   // 32 KB
  __shared__ float s_dbl[32][8];
  const int r0 = blockIdx.x*32;
  const int tid = threadIdx.x;
  #pragma unroll
  for (int q=0;q<4;q++){
    int fid = tid + 256*q;          // 0..1023, 8 bf16 each
    int r  = fid >> 5;
    int g8 = fid & 31;
    uint4 raw = *reinterpret_cast<const uint4*>(xc + (size_t)(r0+r)*256 + g8*8);
    float* dst = &a_sh[r][g8*8];
    unsigned int wv[4] = {raw.x, raw.y, raw.z, raw.w};
    #pragma unroll
    for (int p=0;p<4;p++){
      dst[p*2+0] = uphalf((unsigned short)(wv[p] & 0xffffu));
      dst[p*2+1] = uphalf((unsigned short)(wv[p] >> 16));
    }
  }
  __syncthreads();
  const int c  = tid & 63;      // col (0..39 active)
  const int rg = tid >> 6;      // 0..3 -> rows rg*8 .. rg*8+7
  float acc[8];
  #pragma unroll
  for (int i=0;i<8;i++) acc[i]=0.f;
  if (c < 40){
    for (int k4=0;k4<64;k4++){
      int k = k4*4;
      float w0=Wx[(k+0)*40+c], w1=Wx[(k+1)*40+c], w2=Wx[(k+2)*40+c], w3=Wx[(k+3)*40+c];
      #pragma unroll
      for (int rr=0;rr<8;rr++){
        float4 a = *reinterpret_cast<const float4*>(&a_sh[rg*8+rr][k]);
        acc[rr] = fmaf(a.x,w0, fmaf(a.y,w1, fmaf(a.z,w2, fmaf(a.w,w3, acc[rr]))));
      }
    }
  }
  if (c < 8){
    #pragma unroll
    for (int rr=0;rr<8;rr++) s_dbl[rg*8+rr][c] = acc[rr];
  } else if (c < 40){
    #pragma unroll
    for (int rr=0;rr<8;rr++) BC[(size_t)(r0+rg*8+rr)*32 + (c-8)] = acc[rr];
  }
  __syncthreads();
  // dt phase: thread owns channel d = tid
  float wdt[8];
  #pragma unroll
  for (int j=0;j<8;j++) wdt[j] = Wdt[j*256 + tid];
  float bd = bdt[tid];
  #pragma unroll
  for (int r=0;r<32;r++){
    float v = bd;
    #pragma unroll
    for (int j=0;j<8;j++) v = fmaf(s_dbl[r][j], wdt[j], v);
    float sp = (v > 20.f) ? v : log1pf(__expf(v));
    dtb[(size_t)(r0+r)*256 + tid] = f2bf(sp);
  }
}

// ============ chunked selective scan: exact two-pass decomposition ==========
// pass1: per (b,chunk,d) thread, 16 states in registers. h_end + sum_dt.
__global__ __launch_bounds__(256) void k_scan_p1(const bf16* __restrict__ xc,
      const bf16* __restrict__ dtb, const float* __restrict__ BC,
      const float* __restrict__ Alog,
      float* __restrict__ hend, float* __restrict__ sumdt, int nc, int cl){
  const int blk = blockIdx.x;
  const int b = blk / nc;
  const int c = blk - b*nc;
  const int d = threadIdx.x;
  float An[16];
  {
    const float4* ap = reinterpret_cast<const float4*>(Alog + d*16);
    float4 a0=ap[0], a1=ap[1], a2=ap[2], a3=ap[3];
    float tmp[16] = {a0.x,a0.y,a0.z,a0.w, a1.x,a1.y,a1.z,a1.w,
                     a2.x,a2.y,a2.z,a2.w, a3.x,a3.y,a3.z,a3.w};
    #pragma unroll
    for (int n=0;n<16;n++) An[n] = -__expf(tmp[n]);
  }
  float h[16];
  #pragma unroll
  for (int n=0;n<16;n++) h[n]=0.f;
  float sdt = 0.f;
  const size_t rowbase = (size_t)b*S_ + (size_t)c*cl;
  for (int t=0;t<cl;t++){
    size_t row = rowbase + t;
    float dtv = bf2f(dtb[row*256 + d]);
    float u   = bf2f(xc [row*256 + d]);
    float du  = dtv*u;
    sdt += dtv;
    const float4* bp = reinterpret_cast<const float4*>(BC + row*32);
    float4 B0=bp[0], B1=bp[1], B2=bp[2], B3=bp[3];
    float Bv[16] = {B0.x,B0.y,B0.z,B0.w, B1.x,B1.y,B1.z,B1.w,
                    B2.x,B2.y,B2.z,B2.w, B3.x,B3.y,B3.z,B3.w};
    #pragma unroll
    for (int n=0;n<16;n++)
      h[n] = fmaf(__expf(dtv*An[n]), h[n], du*Bv[n]);
  }
  float4* hp = reinterpret_cast<float4*>(hend + ((size_t)blk*256 + d)*16);
  hp[0] = make_float4(h[0],h[1],h[2],h[3]);
  hp[1] = make_float4(h[4],h[5],h[6],h[7]);
  hp[2] = make_float4(h[8],h[9],h[10],h[11]);
  hp[3] = make_float4(h[12],h[13],h[14],h[15]);
  sumdt[(size_t)blk*256 + d] = sdt;
}

// combine: fold chunk summaries serially; overwrite hend[blk] with carry-IN h0.
__global__ __launch_bounds__(256) void k_scan_comb(const float* __restrict__ Alog,
      const float* __restrict__ sumdt, float* __restrict__ hend, int nc){
  const int b = blockIdx.x;
  const int d = threadIdx.x;
  float An[16];
  {
    const float4* ap = reinterpret_cast<const float4*>(Alog + d*16);
    float4 a0=ap[0], a1=ap[1], a2=ap[2], a3=ap[3];
    float tmp[16] = {a0.x,a0.y,a0.z,a0.w, a1.x,a1.y,a1.z,a1.w,
                     a2.x,a2.y,a2.z,a2.w, a3.x,a3.y,a3.z,a3.w};
    #pragma unroll
    for (int n=0;n<16;n++) An[n] = -__expf(tmp[n]);
  }
  float carry[16];
  #pragma unroll
  for (int n=0;n<16;n++) carry[n]=0.f;
  for (int c=0;c<nc;c++){
    size_t blk = (size_t)b*nc + c;
    float4* hp = reinterpret_cast<float4*>(hend + (blk*256 + d)*16);
    float4 e0=hp[0], e1=hp[1], e2=hp[2], e3=hp[3];
    float sdt = sumdt[blk*256 + d];
    hp[0]=make_float4(carry[0],carry[1],carry[2],carry[3]);
    hp[1]=make_float4(carry[4],carry[5],carry[6],carry[7]);
    hp[2]=make_float4(carry[8],carry[9],carry[10],carry[11]);
    hp[3]=make_float4(carry[12],carry[13],carry[14],carry[15]);
    float he[16] = {e0.x,e0.y,e0.z,e0.w, e1.x,e1.y,e1.z,e1.w,
                    e2.x,e2.y,e2.z,e2.w, e3.x,e3.y,e3.z,e3.w};
    #pragma unroll
    for (int n=0;n<16;n++)
      carry[n] = fmaf(__expf(sdt*An[n]), carry[n], he[n]);
  }
}

// pass2: re-run recurrence seeded with exact carry; emit ym = y*silu(z).
__global__ __launch_bounds__(256) void k_scan_p2(const bf16* __restrict__ xcin,
      const bf16* __restrict__ dtb, const float* __restrict__ BC,
      const bf16* __restrict__ zb, const float* __restrict__ Alog,
      const float* __restrict__ Dpar, const float* __restrict__ hend,
      bf16* __restrict__ ym, int nc, int cl){
  const int blk = blockIdx.x;
  const int b = blk / nc;
  const int c = blk - b*nc;
  const int d = threadIdx.x;
  float An[16];
  {
    const float4* ap = reinterpret_cast<const float4*>(Alog + d*16);
    float4 a0=ap[0], a1=ap[1], a2=ap[2], a3=ap[3];
    float tmp[16] = {a0.x,a0.y,a0.z,a0.w, a1.x,a1.y,a1.z,a1.w,
                     a2.x,a2.y,a2.z,a2.w, a3.x,a3.y,a3.z,a3.w};
    #pragma unroll
    for (int n=0;n<16;n++) An[n] = -__expf(tmp[n]);
  }
  const float Dpv = Dpar[d];
  float h[16];
  {
    const float4* hp = reinterpret_cast<const float4*>(hend + ((size_t)blk*256 + d)*16);
    float4 h0=hp[0], h1=hp[1], h2=hp[2], h3=hp[3];
    h[0]=h0.x; h[1]=h0.y; h[2]=h0.z; h[3]=h0.w;
    h[4]=h1.x; h[5]=h1.y; h[6]=h1.z; h[7]=h1.w;
    h[8]=h2.x; h[9]=h2.y; h[10]=h2.z; h[11]=h2.w;
    h[12]=h3.x; h[13]=h3.y; h[14]=h3.z; h[15]=h3.w;
  }
  const size_t rowbase = (size_t)b*S_ + (size_t)c*cl;
  for (int t=0;t<cl;t++){
    size_t row = rowbase + t;
    float dtv = bf2f(dtb[row*256 + d]);
    float u   = bf2f(xcin[row*256 + d]);
    float du  = dtv*u;
    const float4* bp = reinterpret_cast<const float4*>(BC + row*32);
    float4 B0=bp[0], B1=bp[1], B2=bp[2], B3=bp[3];
    float4 C0=bp[4], C1=bp[5], C2=bp[6], C3=bp[7];
    float Bv[16] = {B0.x,B0.y,B0.z,B0.w, B1.x,B1.y,B1.z,B1.w,
                    B2.x,B2.y,B2.z,B2.w, B3.x,B3.y,B3.z,B3.w};
    float Cv[16] = {C0.x,C0.y,C0.z,C0.w, C1.x,C1.y,C1.z,C1.w,
                    C2.x,C2.y,C2.z,C2.w, C3.x,C3.y,C3.z,C3.w};
    #pragma unroll
    for (int n=0;n<16;n++)
      h[n] = fmaf(__expf(dtv*An[n]), h[n], du*Bv[n]);
    float a0=0.f,a1=0.f,a2=0.f,a3=0.f;
    #pragma unroll
    for (int n=0;n<16;n+=4){
      a0 = fmaf(h[n+0], Cv[n+0], a0);
      a1 = fmaf(h[n+1], Cv[n+1], a1);
      a2 = fmaf(h[n+2], Cv[n+2], a2);
      a3 = fmaf(h[n+3], Cv[n+3], a3);
    }
    float y = fmaf(u, Dpv, (a0+a1)+(a2+a3));
    float zv = bf2f(zb[row*256 + d]);
    float sig = 1.f/(1.f + __expf(-zv));
    ym[row*256 + d] = f2bf(y * zv * sig);
  }
}

// ------- gemm_out: dx = ym @ W_out (K=256, 128 cols), fwd/bwd-fold ---------
__global__ __launch_bounds__(256) void k_gemm_out(const bf16* __restrict__ ym,
      const float* __restrict__ W, bf16* __restrict__ dx, int rev){
  __shared__ __align__(16) float a_sh[32][256];
  const int r0 = blockIdx.x*32;
  const int b  = r0 / S_;
  const int t0 = r0 - b*S_;
  const int tid = threadIdx.x;
  #pragma unroll
  for (int q=0;q<4;q++){
    int fid = tid + 256*q;
    int r  = fid >> 5;
    int g8 = fid & 31;
    uint4 raw = *reinterpret_cast<const uint4*>(ym + (size_t)(r0+r)*256 + g8*8);
    float* dst = &a_sh[r][g8*8];
    unsigned int wv[4] = {raw.x, raw.y, raw.z, raw.w};
    #pragma unroll
    for (int p=0;p<4;p++){
      dst[p*2+0] = uphalf((unsigned short)(wv[p] & 0xffffu));
      dst[p*2+1] = uphalf((unsigned short)(wv[p] >> 16));
    }
  }
  __syncthreads();
  const int c     = tid & 127;
  const int rbase = (tid >> 7) * 16;
  float acc[16];
  #pragma unroll
  for (int i=0;i<16;i++) acc[i]=0.f;
  for (int k4=0;k4<64;k4++){
    int k = k4*4;
    float w0=W[(k+0)*128+c], w1=W[(k+1)*128+c], w2=W[(k+2)*128+c], w3=W[(k+3)*128+c];
    #pragma unroll
    for (int rr=0;rr<16;rr++){
      float4 a = *reinterpret_cast<const float4*>(&a_sh[rbase+rr][k]);
      acc[rr] = fmaf(a.x,w0, fmaf(a.y,w1, fmaf(a.z,w2, fmaf(a.w,w3, acc[rr]))));
    }
  }
  #pragma unroll
  for (int rr=0;rr<16;rr++){
    int t = t0 + rbase + rr;
    size_t drow = (size_t)b*S_ + (rev ? (S_-1 - t) : t);
    if (rev){
      float old = bf2f(dx[drow*128 + c]);
      dx[drow*128 + c] = f2bf(old + 0.5f*acc[rr]);
    } else {
      dx[drow*128 + c] = f2bf(0.5f*acc[rr]);
    }
  }
}

// ------------- combine + layernorm + residual: x += LN(dx) -----------------
__global__ __launch_bounds__(256) void k_combine_ln(const bf16* __restrict__ dx,
      const float* __restrict__ lnw, const float* __restrict__ lnb,
      float* __restrict__ x){
  const int tid  = threadIdx.x;
  const int lane = tid & 63;
  const int row  = blockIdx.x*4 + (tid >> 6);
  const int c0 = lane, c1 = lane + 64;
  float v0 = bf2f(dx[(size_t)row*128 + c0]);
  float v1 = bf2f(dx[(size_t)row*128 + c1]);
  float s = v0 + v1;
  #pragma unroll
  for (int m=1;m<64;m<<=1) s += __shfl_xor(s, m);
  float mu = s * (1.f/128.f);
  float d0 = v0 - mu, d1 = v1 - mu;
  float q = d0*d0 + d1*d1;
  #pragma unroll
  for (int m=1;m<64;m<<=1) q += __shfl_xor(q, m);
  float rs = rsqrtf(q*(1.f/128.f) + 1e-5f);
  x[(size_t)row*128 + c0] += d0*rs*lnw[c0] + lnb[c0];
  x[(size_t)row*128 + c1] += d1*rs*lnw[c1] + lnb[c1];
}

// ---------------- pyramid gather ----------------
__global__ void k_pyramid(const float* __restrict__ x, float* __restrict__ out){
  int idx = blockIdx.x*256 + threadIdx.x;   // 2*32*128*32*32 = 8,388,608
  int j = idx & 31;
  int i = (idx >> 5) & 31;
  int c = (idx >> 10) & 127;
  int m = (idx >> 17) & 31;
  int o = idx >> 22;
  int base = o*1344;
  size_t xm = ((size_t)m * S_ + base) * 128 + c;
  float v = x[xm + (size_t)(320 + i*32 + j)*128]
          + x[xm + (size_t)(64 + (i>>1)*16 + (j>>1))*128]
          + x[xm + (size_t)((i>>2)*8 + (j>>2))*128];
  out[idx] = v;
}

extern "C" void kernel_launch(void* const* d_in, const int* in_sizes, int n_in,
                              void* d_out, int out_size, void* d_ws, size_t ws_size,
                              hipStream_t stream){
  const float* f0   = (const float*)d_in[0];
  const float* f1   = (const float*)d_in[1];
  const float* W_in = (const float*)d_in[2];
  const float* cw   = (const float*)d_in[3];
  const float* cb   = (const float*)d_in[4];
  const float* Wx   = (const float*)d_in[5];
  const float* Wdt  = (const float*)d_in[6];
  const float* bdt  = (const float*)d_in[7];
  const float* Alog = (const float*)d_in[8];
  const float* Dpar = (const float*)d_in[9];
  const float* Wout = (const float*)d_in[10];
  const float* lnw  = (const float*)d_in[11];
  const float* lnb  = (const float*)d_in[12];

  // workspace layout (bytes):
  //   x     fp32  [0,            44,040,192)
  //   xi    bf16  [44,040,192,   88,080,384)   (dtb overlays after conv)
  //   z     bf16  [88,080,384,  132,120,576)
  //   xc    bf16  [132,120,576, 176,160,768)   (ym in-place in scan p2)
  //   BC    fp32  [176,160,768, 187,170,816)   rows*32 (B|C)
  //   sumdt fp32  [187,170,816, 192,675,840)   gap (needs <=1.4MB)
  //   dx    bf16  [192,675,840, 214,695,936)
  //   hend  fp32  [214,695,936, +32*nc*256*16*4)
  const size_t base = 214695936;
  int nc = 0;
  const int cand[5] = {42,21,12,6,2};
  for (int i=0;i<5;i++){
    size_t need = base + (size_t)32*cand[i]*256*16*4;
    if (ws_size >= need){ nc = cand[i]; break; }
  }
  if (nc == 0) return;   // diagnostic guard: clean absmax fail, no fault
  const int cl = S_/nc;

  char* ws = (char*)d_ws;
  float* x     = (float*)(ws + 0);
  bf16*  xi    = (bf16*) (ws + 44040192);
  bf16*  dtb   = (bf16*) (ws + 44040192);
  bf16*  z     = (bf16*) (ws + 88080384);
  bf16*  xc    = (bf16*) (ws + 132120576);
  float* BC    = (float*)(ws + 176160768);
  float* sumdt = (float*)(ws + 187170816);
  bf16*  dx    = (bf16*) (ws + 192675840);
  float* hend  = (float*)(ws + 214695936);

  k_init_x<<<43008,256,0,stream>>>(f0, f1, x);

  for (int l=0;l<2;l++){
    for (int r=0;r<2;r++){
      int lr = l*2 + r;
      const float* Al = Alog + (size_t)lr*256*16;
      k_gemm_in  <<<2688,256,0,stream>>>(x, W_in + (size_t)lr*128*512, xi, z, r);
      k_conv_silu<<<86016,256,0,stream>>>(xi, cw + lr*256*4, cb + lr*256, xc);
      k_gemm_x_dt<<<2688,256,0,stream>>>(xc, Wx + (size_t)lr*256*40,
                                         Wdt + (size_t)lr*8*256, bdt + lr*256, BC, dtb);
      k_scan_p1  <<<32*nc,256,0,stream>>>(xc, dtb, BC, Al, hend, sumdt, nc, cl);
      k_scan_comb<<<32,256,0,stream>>>(Al, sumdt, hend, nc);
      k_scan_p2  <<<32*nc,256,0,stream>>>(xc, dtb, BC, z, Al, Dpar + lr*256,
                                          hend, xc, nc, cl);
      k_gemm_out <<<2688,256,0,stream>>>(xc, Wout + (size_t)lr*256*128, dx, r);
    }
    k_combine_ln<<<21504,256,0,stream>>>(dx, lnw + l*128, lnb + l*128, x);
  }

  k_pyramid<<<32768,256,0,stream>>>(x, (float*)d_out);
}

// Round 7
// 2390.542 us; speedup vs baseline: 5.2242x; 1.2409x over previous
//
#include <hip/hip_runtime.h>
#include <hip/hip_bf16.h>
#include <math.h>

#define B_   32
#define S_   2688
#define D_   128
#define DI_  256
#define DS_  16
#define NROWS (B_*S_)   // 86016

typedef __hip_bfloat16 bf16;
typedef float f32x4 __attribute__((ext_vector_type(4)));
typedef short bf16x8 __attribute__((ext_vector_type(8)));
#define MFMA16(a,b,c) __builtin_amdgcn_mfma_f32_16x16x32_bf16(a,b,c,0,0,0)

__device__ __forceinline__ float bf2f(bf16 v){ return __bfloat162float(v); }
__device__ __forceinline__ bf16  f2bf(float f){ return __float2bfloat16(f); }
__device__ __forceinline__ float uphalf(unsigned short u){
  union { unsigned int i; float f; } c; c.i = ((unsigned int)u) << 16; return c.f;
}
__device__ __forceinline__ unsigned int pk2(float a, float b){
  unsigned int lo = __hip_bfloat16_raw(f2bf(a)).x;
  unsigned int hi = __hip_bfloat16_raw(f2bf(b)).x;
  return lo | (hi << 16);
}

// ---------------- init: x = concat(feat0, feat1) along seq ----------------
__global__ void k_init_x(const float* __restrict__ f0, const float* __restrict__ f1,
                         float* __restrict__ x){
  int idx = blockIdx.x*256 + threadIdx.x;   // 32*2688*128 = 11,010,048
  if (idx >= B_*S_*D_) return;
  const int per_b = S_*D_;        // 344064
  const int half  = 1344*D_;      // 172032
  int b = idx / per_b;
  int rem = idx - b*per_b;
  x[idx] = (rem < half) ? f0[b*half + rem] : f1[b*half + rem - half];
}

// -------- weight convert/transpose: Wt_in[lr][n<512][k<128] bf16 -----------
__global__ void k_wconv_in(const float* __restrict__ W_in, bf16* __restrict__ Wt_in){
  int idx = blockIdx.x*256 + threadIdx.x;   // 1024*256 = 262144
  int k = idx & 127, n = (idx>>7) & 511, lr = idx>>16;
  Wt_in[idx] = f2bf(W_in[((size_t)lr*128 + k)*512 + n]);
}

// ------------- gemm_in (MFMA): [xi|z] = x(_rev) @ W_in ---------------------
// 64-row tile staged once (fp32 -> bf16 pack); 8 column-tiles of 64 looped.
__global__ __launch_bounds__(256) void k_gemm_in_mfma(const float* __restrict__ x,
      const bf16* __restrict__ Wt, bf16* __restrict__ xi, bf16* __restrict__ z, int rev){
  __shared__ __align__(16) unsigned short a_sh[64][136];
  __shared__ __align__(16) unsigned short b_sh[64][136];
  const int r0 = blockIdx.x*64;              // 1344 blocks
  const int b  = r0 / S_;
  const int t0 = r0 - b*S_;
  const int tid = threadIdx.x;
  const int lane = tid & 63, wv = tid >> 6;
  const int wr = (wv>>1)*32, wc = (wv&1)*32;
  const int fr = lane & 15, fk = (lane>>4)*8;

  // stage A (fp32 -> bf16) and B tile 0
  #pragma unroll
  for (int q=0;q<4;q++){
    int fid = tid + 256*q;                   // 0..1023
    int r = fid >> 4, g = fid & 15;
    int t = t0 + r;
    int rg = b*S_ + (rev ? (S_-1 - t) : t);
    const float* src = x + (size_t)rg*128 + g*8;
    float4 v0 = *(const float4*)(src);
    float4 v1 = *(const float4*)(src + 4);
    uint4 pk;
    pk.x = pk2(v0.x, v0.y);
    pk.y = pk2(v0.z, v0.w);
    pk.z = pk2(v1.x, v1.y);
    pk.w = pk2(v1.z, v1.w);
    *(uint4*)&a_sh[r][g*8] = pk;
    *(uint4*)&b_sh[r][g*8] = *(const uint4*)(Wt + (size_t)r*128 + g*8);
  }
  __syncthreads();

  for (int bn=0;bn<8;bn++){
    if (bn){
      __syncthreads();                       // all waves done reading b_sh
      #pragma unroll
      for (int q=0;q<4;q++){
        int fid = tid + 256*q;
        int r = fid >> 4, g = fid & 15;
        *(uint4*)&b_sh[r][g*8] = *(const uint4*)(Wt + (size_t)(bn*64+r)*128 + g*8);
      }
      __syncthreads();
    }
    const f32x4 zero = {0.f,0.f,0.f,0.f};
    f32x4 acc[2][2] = {{zero,zero},{zero,zero}};
    #pragma unroll
    for (int ks=0;ks<4;ks++){
      bf16x8 a0 = *(const bf16x8*)&a_sh[wr+fr   ][ks*32+fk];
      bf16x8 a1 = *(const bf16x8*)&a_sh[wr+16+fr][ks*32+fk];
      bf16x8 b0 = *(const bf16x8*)&b_sh[wc+fr   ][ks*32+fk];
      bf16x8 b1 = *(const bf16x8*)&b_sh[wc+16+fr][ks*32+fk];
      acc[0][0] = MFMA16(a0,b0,acc[0][0]);
      acc[0][1] = MFMA16(a0,b1,acc[0][1]);
      acc[1][0] = MFMA16(a1,b0,acc[1][0]);
      acc[1][1] = MFMA16(a1,b1,acc[1][1]);
    }
    #pragma unroll
    for (int fi=0;fi<2;fi++){
      #pragma unroll
      for (int fj=0;fj<2;fj++){
        int gcol = bn*64 + wc + fj*16 + fr;
        bf16* dst = (gcol < 256) ? xi : z;
        int cc = gcol & 255;
        #pragma unroll
        for (int r=0;r<4;r++){
          size_t row = (size_t)(r0 + wr + fi*16 + (lane>>4)*4 + r);
          dst[row*256 + cc] = f2bf(acc[fi][fj][r]);
        }
      }
    }
  }
}

// ---------------- conv + silu: xc = silu(dwconv_causal(xi)) ----------------
__global__ void k_conv_silu(const bf16* __restrict__ xi, const float* __restrict__ cw,
                            const float* __restrict__ cb, bf16* __restrict__ xc){
  int idx = blockIdx.x*256 + threadIdx.x;   // NROWS*256
  int d   = idx & 255;
  int row = idx >> 8;
  int t   = row % S_;
  float acc = cb[d];
  #pragma unroll
  for (int j=0;j<4;j++){
    int tj = t - 3 + j;
    if (tj >= 0) acc = fmaf(cw[d*4+j], bf2f(xi[(size_t)(row-3+j)*256 + d]), acc);
  }
  float sig = 1.f/(1.f + __expf(-acc));
  xc[idx] = f2bf(acc*sig);
}

// -- gemm_x+dt: xdbl = xc@W_x; BC[row][32]=B|C fp32; dtb[row][d]=softplus bf16
__global__ __launch_bounds__(256) void k_gemm_x_dt(const bf16* __restrict__ xc,
      const float* __restrict__ Wx, const float* __restrict__ Wdt, const float* __restrict__ bdt,
      float* __restrict__ BC, bf16* __restrict__ dtb){
  __shared__ __align__(16) float a_sh[32][256];   // 32 KB
  __shared__ float s_dbl[32][8];
  const int r0 = blockIdx.x*32;
  const int tid = threadIdx.x;
  #pragma unroll
  for (int q=0;q<4;q++){
    int fid = tid + 256*q;          // 0..1023, 8 bf16 each
    int r  = fid >> 5;
    int g8 = fid & 31;
    uint4 raw = *reinterpret_cast<const uint4*>(xc + (size_t)(r0+r)*256 + g8*8);
    float* dst = &a_sh[r][g8*8];
    unsigned int wv[4] = {raw.x, raw.y, raw.z, raw.w};
    #pragma unroll
    for (int p=0;p<4;p++){
      dst[p*2+0] = uphalf((unsigned short)(wv[p] & 0xffffu));
      dst[p*2+1] = uphalf((unsigned short)(wv[p] >> 16));
    }
  }
  __syncthreads();
  const int c  = tid & 63;      // col (0..39 active)
  const int rg = tid >> 6;      // 0..3 -> rows rg*8 .. rg*8+7
  float acc[8];
  #pragma unroll
  for (int i=0;i<8;i++) acc[i]=0.f;
  if (c < 40){
    for (int k4=0;k4<64;k4++){
      int k = k4*4;
      float w0=Wx[(k+0)*40+c], w1=Wx[(k+1)*40+c], w2=Wx[(k+2)*40+c], w3=Wx[(k+3)*40+c];
      #pragma unroll
      for (int rr=0;rr<8;rr++){
        float4 a = *reinterpret_cast<const float4*>(&a_sh[rg*8+rr][k]);
        acc[rr] = fmaf(a.x,w0, fmaf(a.y,w1, fmaf(a.z,w2, fmaf(a.w,w3, acc[rr]))));
      }
    }
  }
  if (c < 8){
    #pragma unroll
    for (int rr=0;rr<8;rr++) s_dbl[rg*8+rr][c] = acc[rr];
  } else if (c < 40){
    #pragma unroll
    for (int rr=0;rr<8;rr++) BC[(size_t)(r0+rg*8+rr)*32 + (c-8)] = acc[rr];
  }
  __syncthreads();
  // dt phase: thread owns channel d = tid
  float wdt[8];
  #pragma unroll
  for (int j=0;j<8;j++) wdt[j] = Wdt[j*256 + tid];
  float bd = bdt[tid];
  #pragma unroll
  for (int r=0;r<32;r++){
    float v = bd;
    #pragma unroll
    for (int j=0;j<8;j++) v = fmaf(s_dbl[r][j], wdt[j], v);
    float sp = (v > 20.f) ? v : log1pf(__expf(v));
    dtb[(size_t)(r0+r)*256 + tid] = f2bf(sp);
  }
}

// ============ chunked selective scan: exact two-pass decomposition ==========
__global__ __launch_bounds__(256) void k_scan_p1(const bf16* __restrict__ xc,
      const bf16* __restrict__ dtb, const float* __restrict__ BC,
      const float* __restrict__ Alog,
      float* __restrict__ hend, float* __restrict__ sumdt, int nc, int cl){
  const int blk = blockIdx.x;
  const int b = blk / nc;
  const int c = blk - b*nc;
  const int d = threadIdx.x;
  float An[16];
  {
    const float4* ap = reinterpret_cast<const float4*>(Alog + d*16);
    float4 a0=ap[0], a1=ap[1], a2=ap[2], a3=ap[3];
    float tmp[16] = {a0.x,a0.y,a0.z,a0.w, a1.x,a1.y,a1.z,a1.w,
                     a2.x,a2.y,a2.z,a2.w, a3.x,a3.y,a3.z,a3.w};
    #pragma unroll
    for (int n=0;n<16;n++) An[n] = -__expf(tmp[n]);
  }
  float h[16];
  #pragma unroll
  for (int n=0;n<16;n++) h[n]=0.f;
  float sdt = 0.f;
  const size_t rowbase = (size_t)b*S_ + (size_t)c*cl;
  for (int t=0;t<cl;t++){
    size_t row = rowbase + t;
    float dtv = bf2f(dtb[row*256 + d]);
    float u   = bf2f(xc [row*256 + d]);
    float du  = dtv*u;
    sdt += dtv;
    const float4* bp = reinterpret_cast<const float4*>(BC + row*32);
    float4 B0=bp[0], B1=bp[1], B2=bp[2], B3=bp[3];
    float Bv[16] = {B0.x,B0.y,B0.z,B0.w, B1.x,B1.y,B1.z,B1.w,
                    B2.x,B2.y,B2.z,B2.w, B3.x,B3.y,B3.z,B3.w};
    #pragma unroll
    for (int n=0;n<16;n++)
      h[n] = fmaf(__expf(dtv*An[n]), h[n], du*Bv[n]);
  }
  float4* hp = reinterpret_cast<float4*>(hend + ((size_t)blk*256 + d)*16);
  hp[0] = make_float4(h[0],h[1],h[2],h[3]);
  hp[1] = make_float4(h[4],h[5],h[6],h[7]);
  hp[2] = make_float4(h[8],h[9],h[10],h[11]);
  hp[3] = make_float4(h[12],h[13],h[14],h[15]);
  sumdt[(size_t)blk*256 + d] = sdt;
}

__global__ __launch_bounds__(256) void k_scan_comb(const float* __restrict__ Alog,
      const float* __restrict__ sumdt, float* __restrict__ hend, int nc){
  const int b = blockIdx.x;
  const int d = threadIdx.x;
  float An[16];
  {
    const float4* ap = reinterpret_cast<const float4*>(Alog + d*16);
    float4 a0=ap[0], a1=ap[1], a2=ap[2], a3=ap[3];
    float tmp[16] = {a0.x,a0.y,a0.z,a0.w, a1.x,a1.y,a1.z,a1.w,
                     a2.x,a2.y,a2.z,a2.w, a3.x,a3.y,a3.z,a3.w};
    #pragma unroll
    for (int n=0;n<16;n++) An[n] = -__expf(tmp[n]);
  }
  float carry[16];
  #pragma unroll
  for (int n=0;n<16;n++) carry[n]=0.f;
  for (int c=0;c<nc;c++){
    size_t blk = (size_t)b*nc + c;
    float4* hp = reinterpret_cast<float4*>(hend + (blk*256 + d)*16);
    float4 e0=hp[0], e1=hp[1], e2=hp[2], e3=hp[3];
    float sdt = sumdt[blk*256 + d];
    hp[0]=make_float4(carry[0],carry[1],carry[2],carry[3]);
    hp[1]=make_float4(carry[4],carry[5],carry[6],carry[7]);
    hp[2]=make_float4(carry[8],carry[9],carry[10],carry[11]);
    hp[3]=make_float4(carry[12],carry[13],carry[14],carry[15]);
    float he[16] = {e0.x,e0.y,e0.z,e0.w, e1.x,e1.y,e1.z,e1.w,
                    e2.x,e2.y,e2.z,e2.w, e3.x,e3.y,e3.z,e3.w};
    #pragma unroll
    for (int n=0;n<16;n++)
      carry[n] = fmaf(__expf(sdt*An[n]), carry[n], he[n]);
  }
}

__global__ __launch_bounds__(256) void k_scan_p2(const bf16* __restrict__ xcin,
      const bf16* __restrict__ dtb, const float* __restrict__ BC,
      const bf16* __restrict__ zb, const float* __restrict__ Alog,
      const float* __restrict__ Dpar, const float* __restrict__ hend,
      bf16* __restrict__ ym, int nc, int cl){
  const int blk = blockIdx.x;
  const int b = blk / nc;
  const int c = blk - b*nc;
  const int d = threadIdx.x;
  float An[16];
  {
    const float4* ap = reinterpret_cast<const float4*>(Alog + d*16);
    float4 a0=ap[0], a1=ap[1], a2=ap[2], a3=ap[3];
    float tmp[16] = {a0.x,a0.y,a0.z,a0.w, a1.x,a1.y,a1.z,a1.w,
                     a2.x,a2.y,a2.z,a2.w, a3.x,a3.y,a3.z,a3.w};
    #pragma unroll
    for (int n=0;n<16;n++) An[n] = -__expf(tmp[n]);
  }
  const float Dpv = Dpar[d];
  float h[16];
  {
    const float4* hp = reinterpret_cast<const float4*>(hend + ((size_t)blk*256 + d)*16);
    float4 h0=hp[0], h1=hp[1], h2=hp[2], h3=hp[3];
    h[0]=h0.x; h[1]=h0.y; h[2]=h0.z; h[3]=h0.w;
    h[4]=h1.x; h[5]=h1.y; h[6]=h1.z; h[7]=h1.w;
    h[8]=h2.x; h[9]=h2.y; h[10]=h2.z; h[11]=h2.w;
    h[12]=h3.x; h[13]=h3.y; h[14]=h3.z; h[15]=h3.w;
  }
  const size_t rowbase = (size_t)b*S_ + (size_t)c*cl;
  for (int t=0;t<cl;t++){
    size_t row = rowbase + t;
    float dtv = bf2f(dtb[row*256 + d]);
    float u   = bf2f(xcin[row*256 + d]);
    float du  = dtv*u;
    const float4* bp = reinterpret_cast<const float4*>(BC + row*32);
    float4 B0=bp[0], B1=bp[1], B2=bp[2], B3=bp[3];
    float4 C0=bp[4], C1=bp[5], C2=bp[6], C3=bp[7];
    float Bv[16] = {B0.x,B0.y,B0.z,B0.w, B1.x,B1.y,B1.z,B1.w,
                    B2.x,B2.y,B2.z,B2.w, B3.x,B3.y,B3.z,B3.w};
    float Cv[16] = {C0.x,C0.y,C0.z,C0.w, C1.x,C1.y,C1.z,C1.w,
                    C2.x,C2.y,C2.z,C2.w, C3.x,C3.y,C3.z,C3.w};
    #pragma unroll
    for (int n=0;n<16;n++)
      h[n] = fmaf(__expf(dtv*An[n]), h[n], du*Bv[n]);
    float a0=0.f,a1=0.f,a2=0.f,a3=0.f;
    #pragma unroll
    for (int n=0;n<16;n+=4){
      a0 = fmaf(h[n+0], Cv[n+0], a0);
      a1 = fmaf(h[n+1], Cv[n+1], a1);
      a2 = fmaf(h[n+2], Cv[n+2], a2);
      a3 = fmaf(h[n+3], Cv[n+3], a3);
    }
    float y = fmaf(u, Dpv, (a0+a1)+(a2+a3));
    float zv = bf2f(zb[row*256 + d]);
    float sig = 1.f/(1.f + __expf(-zv));
    ym[row*256 + d] = f2bf(y * zv * sig);
  }
}

// ------- gemm_out: dx = ym @ W_out (K=256, 128 cols), fwd/bwd-fold ---------
__global__ __launch_bounds__(256) void k_gemm_out(const bf16* __restrict__ ym,
      const float* __restrict__ W, bf16* __restrict__ dx, int rev){
  __shared__ __align__(16) float a_sh[32][256];
  const int r0 = blockIdx.x*32;
  const int b  = r0 / S_;
  const int t0 = r0 - b*S_;
  const int tid = threadIdx.x;
  #pragma unroll
  for (int q=0;q<4;q++){
    int fid = tid + 256*q;
    int r  = fid >> 5;
    int g8 = fid & 31;
    uint4 raw = *reinterpret_cast<const uint4*>(ym + (size_t)(r0+r)*256 + g8*8);
    float* dst = &a_sh[r][g8*8];
    unsigned int wv[4] = {raw.x, raw.y, raw.z, raw.w};
    #pragma unroll
    for (int p=0;p<4;p++){
      dst[p*2+0] = uphalf((unsigned short)(wv[p] & 0xffffu));
      dst[p*2+1] = uphalf((unsigned short)(wv[p] >> 16));
    }
  }
  __syncthreads();
  const int c     = tid & 127;
  const int rbase = (tid >> 7) * 16;
  float acc[16];
  #pragma unroll
  for (int i=0;i<16;i++) acc[i]=0.f;
  for (int k4=0;k4<64;k4++){
    int k = k4*4;
    float w0=W[(k+0)*128+c], w1=W[(k+1)*128+c], w2=W[(k+2)*128+c], w3=W[(k+3)*128+c];
    #pragma unroll
    for (int rr=0;rr<16;rr++){
      float4 a = *reinterpret_cast<const float4*>(&a_sh[rbase+rr][k]);
      acc[rr] = fmaf(a.x,w0, fmaf(a.y,w1, fmaf(a.z,w2, fmaf(a.w,w3, acc[rr]))));
    }
  }
  #pragma unroll
  for (int rr=0;rr<16;rr++){
    int t = t0 + rbase + rr;
    size_t drow = (size_t)b*S_ + (rev ? (S_-1 - t) : t);
    if (rev){
      float old = bf2f(dx[drow*128 + c]);
      dx[drow*128 + c] = f2bf(old + 0.5f*acc[rr]);
    } else {
      dx[drow*128 + c] = f2bf(0.5f*acc[rr]);
    }
  }
}

// ------------- combine + layernorm + residual: x += LN(dx) -----------------
__global__ __launch_bounds__(256) void k_combine_ln(const bf16* __restrict__ dx,
      const float* __restrict__ lnw, const float* __restrict__ lnb,
      float* __restrict__ x){
  const int tid  = threadIdx.x;
  const int lane = tid & 63;
  const int row  = blockIdx.x*4 + (tid >> 6);
  const int c0 = lane, c1 = lane + 64;
  float v0 = bf2f(dx[(size_t)row*128 + c0]);
  float v1 = bf2f(dx[(size_t)row*128 + c1]);
  float s = v0 + v1;
  #pragma unroll
  for (int m=1;m<64;m<<=1) s += __shfl_xor(s, m);
  float mu = s * (1.f/128.f);
  float d0 = v0 - mu, d1 = v1 - mu;
  float q = d0*d0 + d1*d1;
  #pragma unroll
  for (int m=1;m<64;m<<=1) q += __shfl_xor(q, m);
  float rs = rsqrtf(q*(1.f/128.f) + 1e-5f);
  x[(size_t)row*128 + c0] += d0*rs*lnw[c0] + lnb[c0];
  x[(size_t)row*128 + c1] += d1*rs*lnw[c1] + lnb[c1];
}

// ---------------- pyramid gather ----------------
__global__ void k_pyramid(const float* __restrict__ x, float* __restrict__ out){
  int idx = blockIdx.x*256 + threadIdx.x;   // 2*32*128*32*32 = 8,388,608
  int j = idx & 31;
  int i = (idx >> 5) & 31;
  int c = (idx >> 10) & 127;
  int m = (idx >> 17) & 31;
  int o = idx >> 22;
  int base = o*1344;
  size_t xm = ((size_t)m * S_ + base) * 128 + c;
  float v = x[xm + (size_t)(320 + i*32 + j)*128]
          + x[xm + (size_t)(64 + (i>>1)*16 + (j>>1))*128]
          + x[xm + (size_t)((i>>2)*8 + (j>>2))*128];
  out[idx] = v;
}

extern "C" void kernel_launch(void* const* d_in, const int* in_sizes, int n_in,
                              void* d_out, int out_size, void* d_ws, size_t ws_size,
                              hipStream_t stream){
  const float* f0   = (const float*)d_in[0];
  const float* f1   = (const float*)d_in[1];
  const float* W_in = (const float*)d_in[2];
  const float* cw   = (const float*)d_in[3];
  const float* cb   = (const float*)d_in[4];
  const float* Wx   = (const float*)d_in[5];
  const float* Wdt  = (const float*)d_in[6];
  const float* bdt  = (const float*)d_in[7];
  const float* Alog = (const float*)d_in[8];
  const float* Dpar = (const float*)d_in[9];
  const float* Wout = (const float*)d_in[10];
  const float* lnw  = (const float*)d_in[11];
  const float* lnb  = (const float*)d_in[12];

  // workspace layout (bytes) — identical to round 5, Wt_in fits in sumdt gap:
  //   x     fp32  [0,            44,040,192)
  //   xi    bf16  [44,040,192,   88,080,384)   (dtb overlays after conv)
  //   z     bf16  [88,080,384,  132,120,576)
  //   xc    bf16  [132,120,576, 176,160,768)   (ym in-place in scan p2)
  //   BC    fp32  [176,160,768, 187,170,816)   rows*32 (B|C)
  //   sumdt fp32  [187,170,816, 188,547,072)
  //   Wt_in bf16  [188,547,072, 189,071,360)
  //   dx    bf16  [192,675,840, 214,695,936)
  //   hend  fp32  [214,695,936, +32*nc*256*16*4)
  const size_t base = 214695936;
  int nc = 0;
  const int cand[5] = {42,21,12,6,2};
  for (int i=0;i<5;i++){
    size_t need = base + (size_t)32*cand[i]*256*16*4;
    if (ws_size >= need){ nc = cand[i]; break; }
  }
  if (nc == 0) return;   // diagnostic guard: clean absmax fail, no fault
  const int cl = S_/nc;

  char* ws = (char*)d_ws;
  float* x     = (float*)(ws + 0);
  bf16*  xi    = (bf16*) (ws + 44040192);
  bf16*  dtb   = (bf16*) (ws + 44040192);
  bf16*  z     = (bf16*) (ws + 88080384);
  bf16*  xc    = (bf16*) (ws + 132120576);
  float* BC    = (float*)(ws + 176160768);
  float* sumdt = (float*)(ws + 187170816);
  bf16*  Wt_in = (bf16*) (ws + 188547072);
  bf16*  dx    = (bf16*) (ws + 192675840);
  float* hend  = (float*)(ws + 214695936);

  k_init_x  <<<43008,256,0,stream>>>(f0, f1, x);
  k_wconv_in<<<1024,256,0,stream>>>(W_in, Wt_in);

  for (int l=0;l<2;l++){
    for (int r=0;r<2;r++){
      int lr = l*2 + r;
      const float* Al = Alog + (size_t)lr*256*16;
      k_gemm_in_mfma<<<1344,256,0,stream>>>(x, Wt_in + (size_t)lr*65536, xi, z, r);
      k_conv_silu<<<86016,256,0,stream>>>(xi, cw + lr*256*4, cb + lr*256, xc);
      k_gemm_x_dt<<<2688,256,0,stream>>>(xc, Wx + (size_t)lr*256*40,
                                         Wdt + (size_t)lr*8*256, bdt + lr*256, BC, dtb);
      k_scan_p1  <<<32*nc,256,0,stream>>>(xc, dtb, BC, Al, hend, sumdt, nc, cl);
      k_scan_comb<<<32,256,0,stream>>>(Al, sumdt, hend, nc);
      k_scan_p2  <<<32*nc,256,0,stream>>>(xc, dtb, BC, z, Al, Dpar + lr*256,
                                          hend, xc, nc, cl);
      k_gemm_out <<<2688,256,0,stream>>>(xc, Wout + (size_t)lr*256*128, dx, r);
    }
    k_combine_ln<<<21504,256,0,stream>>>(dx, lnw + l*128, lnb + l*128, x);
  }

  k_pyramid<<<32768,256,0,stream>>>(x, (float*)d_out);
}

// Round 8
// 1908.956 us; speedup vs baseline: 6.5422x; 1.2523x over previous
//
#include <hip/hip_runtime.h>
#include <hip/hip_bf16.h>
#include <math.h>

#define B_   32
#define S_   2688
#define D_   128
#define DI_  256
#define DS_  16
#define NROWS (B_*S_)   // 86016

typedef __hip_bfloat16 bf16;
typedef float f32x4 __attribute__((ext_vector_type(4)));
typedef short bf16x8 __attribute__((ext_vector_type(8)));
#define MFMA16(a,b,c) __builtin_amdgcn_mfma_f32_16x16x32_bf16(a,b,c,0,0,0)

__device__ __forceinline__ float bf2f(bf16 v){ return __bfloat162float(v); }
__device__ __forceinline__ bf16  f2bf(float f){ return __float2bfloat16(f); }
__device__ __forceinline__ float uphalf(unsigned short u){
  union { unsigned int i; float f; } c; c.i = ((unsigned int)u) << 16; return c.f;
}
__device__ __forceinline__ unsigned int pk2(float a, float b){
  unsigned int lo = __hip_bfloat16_raw(f2bf(a)).x;
  unsigned int hi = __hip_bfloat16_raw(f2bf(b)).x;
  return lo | (hi << 16);
}

// ---------------- init: x = concat(feat0, feat1) along seq ----------------
__global__ void k_init_x(const float* __restrict__ f0, const float* __restrict__ f1,
                         float* __restrict__ x){
  int idx = blockIdx.x*256 + threadIdx.x;
  if (idx >= B_*S_*D_) return;
  const int per_b = S_*D_;
  const int half  = 1344*D_;
  int b = idx / per_b;
  int rem = idx - b*per_b;
  x[idx] = (rem < half) ? f0[b*half + rem] : f1[b*half + rem - half];
}

// -------- weight convert/transpose to bf16 ---------------------------------
// Wt_in[lr][n<512][k<128], Wt_out[lr][n<128][k<256], Wxt[lr][n<48][k<256]
__global__ void k_wconv(const float* __restrict__ W_in, const float* __restrict__ Wx,
                        const float* __restrict__ W_out,
                        bf16* __restrict__ Wt_in, bf16* __restrict__ Wxt,
                        bf16* __restrict__ Wt_out){
  int idx = blockIdx.x*256 + threadIdx.x;   // 1728*256 = 442368
  if (idx < 262144){
    int k = idx & 127, n = (idx>>7) & 511, lr = idx>>16;
    Wt_in[idx] = f2bf(W_in[((size_t)lr*128 + k)*512 + n]);
    return;
  }
  int i2 = idx - 262144;
  if (i2 < 131072){
    int k = i2 & 255, n = (i2>>8) & 127, lr = i2>>15;
    Wt_out[i2] = f2bf(W_out[((size_t)lr*256 + k)*128 + n]);
    return;
  }
  int i3 = i2 - 131072;
  if (i3 < 49152){
    int k = i3 & 255, nn = i3>>8, n = nn % 48, lr = nn / 48;
    Wxt[i3] = (n < 40) ? f2bf(Wx[((size_t)lr*256 + k)*40 + n]) : f2bf(0.f);
  }
}

// ------------- gemm_in (MFMA): [xi|z] = x(_rev) @ W_in ---------------------
__global__ __launch_bounds__(256) void k_gemm_in_mfma(const float* __restrict__ x,
      const bf16* __restrict__ Wt, bf16* __restrict__ xi, bf16* __restrict__ z, int rev){
  __shared__ __align__(16) unsigned short a_sh[64][136];
  __shared__ __align__(16) unsigned short b_sh[64][136];
  const int r0 = blockIdx.x*64;              // 1344 blocks
  const int b  = r0 / S_;
  const int t0 = r0 - b*S_;
  const int tid = threadIdx.x;
  const int lane = tid & 63, wv = tid >> 6;
  const int wr = (wv>>1)*32, wc = (wv&1)*32;
  const int fr = lane & 15, fk = (lane>>4)*8;

  #pragma unroll
  for (int q=0;q<4;q++){
    int fid = tid + 256*q;
    int r = fid >> 4, g = fid & 15;
    int t = t0 + r;
    int rg = b*S_ + (rev ? (S_-1 - t) : t);
    const float* src = x + (size_t)rg*128 + g*8;
    float4 v0 = *(const float4*)(src);
    float4 v1 = *(const float4*)(src + 4);
    uint4 pk;
    pk.x = pk2(v0.x, v0.y);
    pk.y = pk2(v0.z, v0.w);
    pk.z = pk2(v1.x, v1.y);
    pk.w = pk2(v1.z, v1.w);
    *(uint4*)&a_sh[r][g*8] = pk;
    *(uint4*)&b_sh[r][g*8] = *(const uint4*)(Wt + (size_t)r*128 + g*8);
  }
  __syncthreads();

  for (int bn=0;bn<8;bn++){
    if (bn){
      __syncthreads();
      #pragma unroll
      for (int q=0;q<4;q++){
        int fid = tid + 256*q;
        int r = fid >> 4, g = fid & 15;
        *(uint4*)&b_sh[r][g*8] = *(const uint4*)(Wt + (size_t)(bn*64+r)*128 + g*8);
      }
      __syncthreads();
    }
    const f32x4 zero = {0.f,0.f,0.f,0.f};
    f32x4 acc[2][2] = {{zero,zero},{zero,zero}};
    #pragma unroll
    for (int ks=0;ks<4;ks++){
      bf16x8 a0 = *(const bf16x8*)&a_sh[wr+fr   ][ks*32+fk];
      bf16x8 a1 = *(const bf16x8*)&a_sh[wr+16+fr][ks*32+fk];
      bf16x8 b0 = *(const bf16x8*)&b_sh[wc+fr   ][ks*32+fk];
      bf16x8 b1 = *(const bf16x8*)&b_sh[wc+16+fr][ks*32+fk];
      acc[0][0] = MFMA16(a0,b0,acc[0][0]);
      acc[0][1] = MFMA16(a0,b1,acc[0][1]);
      acc[1][0] = MFMA16(a1,b0,acc[1][0]);
      acc[1][1] = MFMA16(a1,b1,acc[1][1]);
    }
    #pragma unroll
    for (int fi=0;fi<2;fi++){
      #pragma unroll
      for (int fj=0;fj<2;fj++){
        int gcol = bn*64 + wc + fj*16 + fr;
        bf16* dst = (gcol < 256) ? xi : z;
        int cc = gcol & 255;
        #pragma unroll
        for (int r=0;r<4;r++){
          size_t row = (size_t)(r0 + wr + fi*16 + (lane>>4)*4 + r);
          dst[row*256 + cc] = f2bf(acc[fi][fj][r]);
        }
      }
    }
  }
}

// ---------------- conv + silu: xc = silu(dwconv_causal(xi)) ----------------
__global__ void k_conv_silu(const bf16* __restrict__ xi, const float* __restrict__ cw,
                            const float* __restrict__ cb, bf16* __restrict__ xc){
  int idx = blockIdx.x*256 + threadIdx.x;
  int d   = idx & 255;
  int row = idx >> 8;
  int t   = row % S_;
  float acc = cb[d];
  #pragma unroll
  for (int j=0;j<4;j++){
    int tj = t - 3 + j;
    if (tj >= 0) acc = fmaf(cw[d*4+j], bf2f(xi[(size_t)(row-3+j)*256 + d]), acc);
  }
  float sig = 1.f/(1.f + __expf(-acc));
  xc[idx] = f2bf(acc*sig);
}

// -- gemm_x+dt (MFMA): xdbl = xc@Wx; BC[row][32]=B|C; dtb=softplus(dbl@Wdt+b)
__global__ __launch_bounds__(256) void k_gemm_x_dt_mfma(const bf16* __restrict__ xc,
      const bf16* __restrict__ Wxt, const float* __restrict__ Wdt, const float* __restrict__ bdt,
      float* __restrict__ BC, bf16* __restrict__ dtb){
  __shared__ __align__(16) unsigned short a_sh[64][136];
  __shared__ __align__(16) unsigned short b_sh[48][136];
  __shared__ float s_dbl[64][8];
  const int r0 = blockIdx.x*64;              // 1344 blocks
  const int tid = threadIdx.x;
  const int lane = tid & 63, wv = tid >> 6;
  const int fr = lane & 15, fk = (lane>>4)*8;
  const f32x4 zero = {0.f,0.f,0.f,0.f};
  f32x4 acc[3] = {zero,zero,zero};

  for (int kst=0;kst<2;kst++){
    if (kst) __syncthreads();
    #pragma unroll
    for (int q=0;q<4;q++){
      int fid = tid + 256*q;
      int r = fid >> 4, g = fid & 15;
      *(uint4*)&a_sh[r][g*8] = *(const uint4*)(xc + (size_t)(r0+r)*256 + kst*128 + g*8);
      if (fid < 768)
        *(uint4*)&b_sh[r][g*8] = *(const uint4*)(Wxt + (size_t)r*256 + kst*128 + g*8);
    }
    __syncthreads();
    #pragma unroll
    for (int ks=0;ks<4;ks++){
      bf16x8 a0 = *(const bf16x8*)&a_sh[wv*16+fr][ks*32+fk];
      #pragma unroll
      for (int fj=0;fj<3;fj++){
        bf16x8 bb = *(const bf16x8*)&b_sh[fj*16+fr][ks*32+fk];
        acc[fj] = MFMA16(a0,bb,acc[fj]);
      }
    }
  }
  // epilogue: cols 0..7 -> s_dbl, cols 8..39 -> BC, cols 40..47 discard
  #pragma unroll
  for (int fj=0;fj<3;fj++){
    int col = fj*16 + fr;
    #pragma unroll
    for (int r=0;r<4;r++){
      int rr = wv*16 + (lane>>4)*4 + r;
      size_t row = (size_t)(r0 + rr);
      if (col < 8)       s_dbl[rr][col] = acc[fj][r];
      else if (col < 40) BC[row*32 + (col-8)] = acc[fj][r];
    }
  }
  __syncthreads();
  // dt phase: thread owns channel d = tid, 64 rows
  float wdt[8];
  #pragma unroll
  for (int j=0;j<8;j++) wdt[j] = Wdt[j*256 + tid];
  float bd = bdt[tid];
  #pragma unroll
  for (int r=0;r<64;r++){
    float v = bd;
    #pragma unroll
    for (int j=0;j<8;j++) v = fmaf(s_dbl[r][j], wdt[j], v);
    float sp = (v > 20.f) ? v : log1pf(__expf(v));
    dtb[(size_t)(r0+r)*256 + tid] = f2bf(sp);
  }
}

// ============ chunked selective scan: exact two-pass decomposition ==========
__global__ __launch_bounds__(256) void k_scan_p1(const bf16* __restrict__ xc,
      const bf16* __restrict__ dtb, const float* __restrict__ BC,
      const float* __restrict__ Alog,
      float* __restrict__ hend, float* __restrict__ sumdt, int nc, int cl){
  const int blk = blockIdx.x;
  const int b = blk / nc;
  const int c = blk - b*nc;
  const int d = threadIdx.x;
  float An[16];
  {
    const float4* ap = reinterpret_cast<const float4*>(Alog + d*16);
    float4 a0=ap[0], a1=ap[1], a2=ap[2], a3=ap[3];
    float tmp[16] = {a0.x,a0.y,a0.z,a0.w, a1.x,a1.y,a1.z,a1.w,
                     a2.x,a2.y,a2.z,a2.w, a3.x,a3.y,a3.z,a3.w};
    #pragma unroll
    for (int n=0;n<16;n++) An[n] = -__expf(tmp[n]);
  }
  float h[16];
  #pragma unroll
  for (int n=0;n<16;n++) h[n]=0.f;
  float sdt = 0.f;
  const size_t rowbase = (size_t)b*S_ + (size_t)c*cl;
  for (int t=0;t<cl;t++){
    size_t row = rowbase + t;
    float dtv = bf2f(dtb[row*256 + d]);
    float u   = bf2f(xc [row*256 + d]);
    float du  = dtv*u;
    sdt += dtv;
    const float4* bp = reinterpret_cast<const float4*>(BC + row*32);
    float4 B0=bp[0], B1=bp[1], B2=bp[2], B3=bp[3];
    float Bv[16] = {B0.x,B0.y,B0.z,B0.w, B1.x,B1.y,B1.z,B1.w,
                    B2.x,B2.y,B2.z,B2.w, B3.x,B3.y,B3.z,B3.w};
    #pragma unroll
    for (int n=0;n<16;n++)
      h[n] = fmaf(__expf(dtv*An[n]), h[n], du*Bv[n]);
  }
  float4* hp = reinterpret_cast<float4*>(hend + ((size_t)blk*256 + d)*16);
  hp[0] = make_float4(h[0],h[1],h[2],h[3]);
  hp[1] = make_float4(h[4],h[5],h[6],h[7]);
  hp[2] = make_float4(h[8],h[9],h[10],h[11]);
  hp[3] = make_float4(h[12],h[13],h[14],h[15]);
  sumdt[(size_t)blk*256 + d] = sdt;
}

__global__ __launch_bounds__(256) void k_scan_comb(const float* __restrict__ Alog,
      const float* __restrict__ sumdt, float* __restrict__ hend, int nc){
  const int b = blockIdx.x;
  const int d = threadIdx.x;
  float An[16];
  {
    const float4* ap = reinterpret_cast<const float4*>(Alog + d*16);
    float4 a0=ap[0], a1=ap[1], a2=ap[2], a3=ap[3];
    float tmp[16] = {a0.x,a0.y,a0.z,a0.w, a1.x,a1.y,a1.z,a1.w,
                     a2.x,a2.y,a2.z,a2.w, a3.x,a3.y,a3.z,a3.w};
    #pragma unroll
    for (int n=0;n<16;n++) An[n] = -__expf(tmp[n]);
  }
  float carry[16];
  #pragma unroll
  for (int n=0;n<16;n++) carry[n]=0.f;
  for (int c=0;c<nc;c++){
    size_t blk = (size_t)b*nc + c;
    float4* hp = reinterpret_cast<float4*>(hend + (blk*256 + d)*16);
    float4 e0=hp[0], e1=hp[1], e2=hp[2], e3=hp[3];
    float sdt = sumdt[blk*256 + d];
    hp[0]=make_float4(carry[0],carry[1],carry[2],carry[3]);
    hp[1]=make_float4(carry[4],carry[5],carry[6],carry[7]);
    hp[2]=make_float4(carry[8],carry[9],carry[10],carry[11]);
    hp[3]=make_float4(carry[12],carry[13],carry[14],carry[15]);
    float he[16] = {e0.x,e0.y,e0.z,e0.w, e1.x,e1.y,e1.z,e1.w,
                    e2.x,e2.y,e2.z,e2.w, e3.x,e3.y,e3.z,e3.w};
    #pragma unroll
    for (int n=0;n<16;n++)
      carry[n] = fmaf(__expf(sdt*An[n]), carry[n], he[n]);
  }
}

__global__ __launch_bounds__(256) void k_scan_p2(const bf16* __restrict__ xcin,
      const bf16* __restrict__ dtb, const float* __restrict__ BC,
      const bf16* __restrict__ zb, const float* __restrict__ Alog,
      const float* __restrict__ Dpar, const float* __restrict__ hend,
      bf16* __restrict__ ym, int nc, int cl){
  const int blk = blockIdx.x;
  const int b = blk / nc;
  const int c = blk - b*nc;
  const int d = threadIdx.x;
  float An[16];
  {
    const float4* ap = reinterpret_cast<const float4*>(Alog + d*16);
    float4 a0=ap[0], a1=ap[1], a2=ap[2], a3=ap[3];
    float tmp[16] = {a0.x,a0.y,a0.z,a0.w, a1.x,a1.y,a1.z,a1.w,
                     a2.x,a2.y,a2.z,a2.w, a3.x,a3.y,a3.z,a3.w};
    #pragma unroll
    for (int n=0;n<16;n++) An[n] = -__expf(tmp[n]);
  }
  const float Dpv = Dpar[d];
  float h[16];
  {
    const float4* hp = reinterpret_cast<const float4*>(hend + ((size_t)blk*256 + d)*16);
    float4 h0=hp[0], h1=hp[1], h2=hp[2], h3=hp[3];
    h[0]=h0.x; h[1]=h0.y; h[2]=h0.z; h[3]=h0.w;
    h[4]=h1.x; h[5]=h1.y; h[6]=h1.z; h[7]=h1.w;
    h[8]=h2.x; h[9]=h2.y; h[10]=h2.z; h[11]=h2.w;
    h[12]=h3.x; h[13]=h3.y; h[14]=h3.z; h[15]=h3.w;
  }
  const size_t rowbase = (size_t)b*S_ + (size_t)c*cl;
  for (int t=0;t<cl;t++){
    size_t row = rowbase + t;
    float dtv = bf2f(dtb[row*256 + d]);
    float u   = bf2f(xcin[row*256 + d]);
    float du  = dtv*u;
    const float4* bp = reinterpret_cast<const float4*>(BC + row*32);
    float4 B0=bp[0], B1=bp[1], B2=bp[2], B3=bp[3];
    float4 C0=bp[4], C1=bp[5], C2=bp[6], C3=bp[7];
    float Bv[16] = {B0.x,B0.y,B0.z,B0.w, B1.x,B1.y,B1.z,B1.w,
                    B2.x,B2.y,B2.z,B2.w, B3.x,B3.y,B3.z,B3.w};
    float Cv[16] = {C0.x,C0.y,C0.z,C0.w, C1.x,C1.y,C1.z,C1.w,
                    C2.x,C2.y,C2.z,C2.w, C3.x,C3.y,C3.z,C3.w};
    #pragma unroll
    for (int n=0;n<16;n++)
      h[n] = fmaf(__expf(dtv*An[n]), h[n], du*Bv[n]);
    float a0=0.f,a1=0.f,a2=0.f,a3=0.f;
    #pragma unroll
    for (int n=0;n<16;n+=4){
      a0 = fmaf(h[n+0], Cv[n+0], a0);
      a1 = fmaf(h[n+1], Cv[n+1], a1);
      a2 = fmaf(h[n+2], Cv[n+2], a2);
      a3 = fmaf(h[n+3], Cv[n+3], a3);
    }
    float y = fmaf(u, Dpv, (a0+a1)+(a2+a3));
    float zv = bf2f(zb[row*256 + d]);
    float sig = 1.f/(1.f + __expf(-zv));
    ym[row*256 + d] = f2bf(y * zv * sig);
  }
}

// ------- gemm_out (MFMA): dx = ym @ W_out (K=256), fwd/bwd-fold ------------
__global__ __launch_bounds__(256) void k_gemm_out_mfma(const bf16* __restrict__ ym,
      const bf16* __restrict__ Wt, bf16* __restrict__ dx, int rev){
  __shared__ __align__(16) unsigned short a_sh[64][136];
  __shared__ __align__(16) unsigned short b_sh[64][136];
  const int blk = blockIdx.x;                // 1344 * 2
  const int bm = blk >> 1, bn = blk & 1;
  const int r0 = bm*64, n0 = bn*64;
  const int b  = r0 / S_;
  const int t0 = r0 - b*S_;
  const int tid = threadIdx.x;
  const int lane = tid & 63, wv = tid >> 6;
  const int wr = (wv>>1)*32, wc = (wv&1)*32;
  const int fr = lane & 15, fk = (lane>>4)*8;
  const f32x4 zero = {0.f,0.f,0.f,0.f};
  f32x4 acc[2][2] = {{zero,zero},{zero,zero}};

  for (int kst=0;kst<2;kst++){
    if (kst) __syncthreads();
    #pragma unroll
    for (int q=0;q<4;q++){
      int fid = tid + 256*q;
      int r = fid >> 4, g = fid & 15;
      *(uint4*)&a_sh[r][g*8] = *(const uint4*)(ym + (size_t)(r0+r)*256 + kst*128 + g*8);
      *(uint4*)&b_sh[r][g*8] = *(const uint4*)(Wt + (size_t)(n0+r)*256 + kst*128 + g*8);
    }
    __syncthreads();
    #pragma unroll
    for (int ks=0;ks<4;ks++){
      bf16x8 a0 = *(const bf16x8*)&a_sh[wr+fr   ][ks*32+fk];
      bf16x8 a1 = *(const bf16x8*)&a_sh[wr+16+fr][ks*32+fk];
      bf16x8 b0 = *(const bf16x8*)&b_sh[wc+fr   ][ks*32+fk];
      bf16x8 b1 = *(const bf16x8*)&b_sh[wc+16+fr][ks*32+fk];
      acc[0][0] = MFMA16(a0,b0,acc[0][0]);
      acc[0][1] = MFMA16(a0,b1,acc[0][1]);
      acc[1][0] = MFMA16(a1,b0,acc[1][0]);
      acc[1][1] = MFMA16(a1,b1,acc[1][1]);
    }
  }
  #pragma unroll
  for (int fi=0;fi<2;fi++){
    #pragma unroll
    for (int fj=0;fj<2;fj++){
      int c = n0 + wc + fj*16 + fr;
      #pragma unroll
      for (int r=0;r<4;r++){
        int t = t0 + wr + fi*16 + (lane>>4)*4 + r;
        size_t drow = (size_t)b*S_ + (rev ? (S_-1 - t) : t);
        if (rev){
          float old = bf2f(dx[drow*128 + c]);
          dx[drow*128 + c] = f2bf(old + 0.5f*acc[fi][fj][r]);
        } else {
          dx[drow*128 + c] = f2bf(0.5f*acc[fi][fj][r]);
        }
      }
    }
  }
}

// ------------- combine + layernorm + residual: x += LN(dx) -----------------
__global__ __launch_bounds__(256) void k_combine_ln(const bf16* __restrict__ dx,
      const float* __restrict__ lnw, const float* __restrict__ lnb,
      float* __restrict__ x){
  const int tid  = threadIdx.x;
  const int lane = tid & 63;
  const int row  = blockIdx.x*4 + (tid >> 6);
  const int c0 = lane, c1 = lane + 64;
  float v0 = bf2f(dx[(size_t)row*128 + c0]);
  float v1 = bf2f(dx[(size_t)row*128 + c1]);
  float s = v0 + v1;
  #pragma unroll
  for (int m=1;m<64;m<<=1) s += __shfl_xor(s, m);
  float mu = s * (1.f/128.f);
  float d0 = v0 - mu, d1 = v1 - mu;
  float q = d0*d0 + d1*d1;
  #pragma unroll
  for (int m=1;m<64;m<<=1) q += __shfl_xor(q, m);
  float rs = rsqrtf(q*(1.f/128.f) + 1e-5f);
  x[(size_t)row*128 + c0] += d0*rs*lnw[c0] + lnb[c0];
  x[(size_t)row*128 + c1] += d1*rs*lnw[c1] + lnb[c1];
}

// ---------------- pyramid gather ----------------
__global__ void k_pyramid(const float* __restrict__ x, float* __restrict__ out){
  int idx = blockIdx.x*256 + threadIdx.x;
  int j = idx & 31;
  int i = (idx >> 5) & 31;
  int c = (idx >> 10) & 127;
  int m = (idx >> 17) & 31;
  int o = idx >> 22;
  int base = o*1344;
  size_t xm = ((size_t)m * S_ + base) * 128 + c;
  float v = x[xm + (size_t)(320 + i*32 + j)*128]
          + x[xm + (size_t)(64 + (i>>1)*16 + (j>>1))*128]
          + x[xm + (size_t)((i>>2)*8 + (j>>2))*128];
  out[idx] = v;
}

extern "C" void kernel_launch(void* const* d_in, const int* in_sizes, int n_in,
                              void* d_out, int out_size, void* d_ws, size_t ws_size,
                              hipStream_t stream){
  const float* f0   = (const float*)d_in[0];
  const float* f1   = (const float*)d_in[1];
  const float* W_in = (const float*)d_in[2];
  const float* cw   = (const float*)d_in[3];
  const float* cb   = (const float*)d_in[4];
  const float* Wx   = (const float*)d_in[5];
  const float* Wdt  = (const float*)d_in[6];
  const float* bdt  = (const float*)d_in[7];
  const float* Alog = (const float*)d_in[8];
  const float* Dpar = (const float*)d_in[9];
  const float* Wout = (const float*)d_in[10];
  const float* lnw  = (const float*)d_in[11];
  const float* lnb  = (const float*)d_in[12];

  // workspace layout (bytes):
  //   x      fp32  [0,            44,040,192)
  //   xi     bf16  [44,040,192,   88,080,384)   (dtb overlays after conv)
  //   z      bf16  [88,080,384,  132,120,576)
  //   xc     bf16  [132,120,576, 176,160,768)   (ym in-place in scan p2)
  //   BC     fp32  [176,160,768, 187,170,816)   rows*32 (B|C)
  //   sumdt  fp32  [187,170,816, 188,547,072)
  //   Wt_in  bf16  [188,547,072, 189,071,360)
  //   Wt_out bf16  [189,071,360, 189,333,504)
  //   Wxt    bf16  [189,333,504, 189,431,808)
  //   dx     bf16  [192,675,840, 214,695,936)
  //   hend   fp32  [214,695,936, +32*nc*256*16*4)
  const size_t base = 214695936;
  int nc = 0;
  const int cand[5] = {42,21,12,6,2};
  for (int i=0;i<5;i++){
    size_t need = base + (size_t)32*cand[i]*256*16*4;
    if (ws_size >= need){ nc = cand[i]; break; }
  }
  if (nc == 0) return;
  const int cl = S_/nc;

  char* ws = (char*)d_ws;
  float* x      = (float*)(ws + 0);
  bf16*  xi     = (bf16*) (ws + 44040192);
  bf16*  dtb    = (bf16*) (ws + 44040192);
  bf16*  z      = (bf16*) (ws + 88080384);
  bf16*  xc     = (bf16*) (ws + 132120576);
  float* BC     = (float*)(ws + 176160768);
  float* sumdt  = (float*)(ws + 187170816);
  bf16*  Wt_in  = (bf16*) (ws + 188547072);
  bf16*  Wt_out = (bf16*) (ws + 189071360);
  bf16*  Wxt    = (bf16*) (ws + 189333504);
  bf16*  dx     = (bf16*) (ws + 192675840);
  float* hend   = (float*)(ws + 214695936);

  k_init_x<<<43008,256,0,stream>>>(f0, f1, x);
  k_wconv <<<1728,256,0,stream>>>(W_in, Wx, Wout, Wt_in, Wxt, Wt_out);

  for (int l=0;l<2;l++){
    for (int r=0;r<2;r++){
      int lr = l*2 + r;
      const float* Al = Alog + (size_t)lr*256*16;
      k_gemm_in_mfma  <<<1344,256,0,stream>>>(x, Wt_in + (size_t)lr*65536, xi, z, r);
      k_conv_silu     <<<86016,256,0,stream>>>(xi, cw + lr*256*4, cb + lr*256, xc);
      k_gemm_x_dt_mfma<<<1344,256,0,stream>>>(xc, Wxt + (size_t)lr*12288,
                                              Wdt + (size_t)lr*8*256, bdt + lr*256, BC, dtb);
      k_scan_p1  <<<32*nc,256,0,stream>>>(xc, dtb, BC, Al, hend, sumdt, nc, cl);
      k_scan_comb<<<32,256,0,stream>>>(Al, sumdt, hend, nc);
      k_scan_p2  <<<32*nc,256,0,stream>>>(xc, dtb, BC, z, Al, Dpar + lr*256,
                                          hend, xc, nc, cl);
      k_gemm_out_mfma <<<2688,256,0,stream>>>(xc, Wt_out + (size_t)lr*32768, dx, r);
    }
    k_combine_ln<<<21504,256,0,stream>>>(dx, lnw + l*128, lnb + l*128, x);
  }

  k_pyramid<<<32768,256,0,stream>>>(x, (float*)d_out);
}

// Round 9
// 1597.501 us; speedup vs baseline: 7.8177x; 1.1950x over previous
//
#include <hip/hip_runtime.h>
#include <hip/hip_bf16.h>
#include <math.h>

#define B_   32
#define S_   2688
#define D_   128
#define DI_  256
#define DS_  16
#define NROWS (B_*S_)   // 86016

typedef __hip_bfloat16 bf16;
typedef float f32x4 __attribute__((ext_vector_type(4)));
typedef short bf16x8 __attribute__((ext_vector_type(8)));
#define MFMA16(a,b,c) __builtin_amdgcn_mfma_f32_16x16x32_bf16(a,b,c,0,0,0)

__device__ __forceinline__ float bf2f(bf16 v){ return __bfloat162float(v); }
__device__ __forceinline__ bf16  f2bf(float f){ return __float2bfloat16(f); }
__device__ __forceinline__ float uphalf(unsigned short u){
  union { unsigned int i; float f; } c; c.i = ((unsigned int)u) << 16; return c.f;
}
__device__ __forceinline__ unsigned int pk2(float a, float b){
  unsigned int lo = __hip_bfloat16_raw(f2bf(a)).x;
  unsigned int hi = __hip_bfloat16_raw(f2bf(b)).x;
  return lo | (hi << 16);
}

// ---------------- init: x = concat(feat0, feat1) along seq ----------------
__global__ void k_init_x(const float* __restrict__ f0, const float* __restrict__ f1,
                         float* __restrict__ x){
  int idx = blockIdx.x*256 + threadIdx.x;
  if (idx >= B_*S_*D_) return;
  const int per_b = S_*D_;
  const int half  = 1344*D_;
  int b = idx / per_b;
  int rem = idx - b*per_b;
  x[idx] = (rem < half) ? f0[b*half + rem] : f1[b*half + rem - half];
}

// -------- weight convert/transpose to bf16 ---------------------------------
__global__ void k_wconv(const float* __restrict__ W_in, const float* __restrict__ Wx,
                        const float* __restrict__ W_out,
                        bf16* __restrict__ Wt_in, bf16* __restrict__ Wxt,
                        bf16* __restrict__ Wt_out){
  int idx = blockIdx.x*256 + threadIdx.x;   // 1728*256 = 442368
  if (idx < 262144){
    int k = idx & 127, n = (idx>>7) & 511, lr = idx>>16;
    Wt_in[idx] = f2bf(W_in[((size_t)lr*128 + k)*512 + n]);
    return;
  }
  int i2 = idx - 262144;
  if (i2 < 131072){
    int k = i2 & 255, n = (i2>>8) & 127, lr = i2>>15;
    Wt_out[i2] = f2bf(W_out[((size_t)lr*256 + k)*128 + n]);
    return;
  }
  int i3 = i2 - 131072;
  if (i3 < 49152){
    int k = i3 & 255, nn = i3>>8, n = nn % 48, lr = nn / 48;
    Wxt[i3] = (n < 40) ? f2bf(Wx[((size_t)lr*256 + k)*40 + n]) : f2bf(0.f);
  }
}

// ------------- gemm_in (MFMA): [xi|z] = x(_rev) @ W_in ---------------------
__global__ __launch_bounds__(256) void k_gemm_in_mfma(const float* __restrict__ x,
      const bf16* __restrict__ Wt, bf16* __restrict__ xi, bf16* __restrict__ z, int rev){
  __shared__ __align__(16) unsigned short a_sh[64][136];
  __shared__ __align__(16) unsigned short b_sh[64][136];
  const int r0 = blockIdx.x*64;              // 1344 blocks
  const int b  = r0 / S_;
  const int t0 = r0 - b*S_;
  const int tid = threadIdx.x;
  const int lane = tid & 63, wv = tid >> 6;
  const int wr = (wv>>1)*32, wc = (wv&1)*32;
  const int fr = lane & 15, fk = (lane>>4)*8;

  #pragma unroll
  for (int q=0;q<4;q++){
    int fid = tid + 256*q;
    int r = fid >> 4, g = fid & 15;
    int t = t0 + r;
    int rg = b*S_ + (rev ? (S_-1 - t) : t);
    const float* src = x + (size_t)rg*128 + g*8;
    float4 v0 = *(const float4*)(src);
    float4 v1 = *(const float4*)(src + 4);
    uint4 pk;
    pk.x = pk2(v0.x, v0.y);
    pk.y = pk2(v0.z, v0.w);
    pk.z = pk2(v1.x, v1.y);
    pk.w = pk2(v1.z, v1.w);
    *(uint4*)&a_sh[r][g*8] = pk;
    *(uint4*)&b_sh[r][g*8] = *(const uint4*)(Wt + (size_t)r*128 + g*8);
  }
  __syncthreads();

  for (int bn=0;bn<8;bn++){
    if (bn){
      __syncthreads();
      #pragma unroll
      for (int q=0;q<4;q++){
        int fid = tid + 256*q;
        int r = fid >> 4, g = fid & 15;
        *(uint4*)&b_sh[r][g*8] = *(const uint4*)(Wt + (size_t)(bn*64+r)*128 + g*8);
      }
      __syncthreads();
    }
    const f32x4 zero = {0.f,0.f,0.f,0.f};
    f32x4 acc[2][2] = {{zero,zero},{zero,zero}};
    #pragma unroll
    for (int ks=0;ks<4;ks++){
      bf16x8 a0 = *(const bf16x8*)&a_sh[wr+fr   ][ks*32+fk];
      bf16x8 a1 = *(const bf16x8*)&a_sh[wr+16+fr][ks*32+fk];
      bf16x8 b0 = *(const bf16x8*)&b_sh[wc+fr   ][ks*32+fk];
      bf16x8 b1 = *(const bf16x8*)&b_sh[wc+16+fr][ks*32+fk];
      acc[0][0] = MFMA16(a0,b0,acc[0][0]);
      acc[0][1] = MFMA16(a0,b1,acc[0][1]);
      acc[1][0] = MFMA16(a1,b0,acc[1][0]);
      acc[1][1] = MFMA16(a1,b1,acc[1][1]);
    }
    #pragma unroll
    for (int fi=0;fi<2;fi++){
      #pragma unroll
      for (int fj=0;fj<2;fj++){
        int gcol = bn*64 + wc + fj*16 + fr;
        bf16* dst = (gcol < 256) ? xi : z;
        int cc = gcol & 255;
        #pragma unroll
        for (int r=0;r<4;r++){
          size_t row = (size_t)(r0 + wr + fi*16 + (lane>>4)*4 + r);
          dst[row*256 + cc] = f2bf(acc[fi][fj][r]);
        }
      }
    }
  }
}

// ------- conv + silu (vectorized: 4 rows x 8 channels per thread) ----------
__global__ __launch_bounds__(256) void k_conv_silu(const bf16* __restrict__ xi,
      const float* __restrict__ cw, const float* __restrict__ cb,
      bf16* __restrict__ xc){
  int gid = blockIdx.x*256 + threadIdx.x;    // 2688 blocks -> 688128 threads
  int dg  = gid & 31;                        // channel group (8 ch)
  int rg  = gid >> 5;                        // row group (4 rows), 0..21503
  const int r0 = rg*4;
  const int t0 = r0 % S_;                    // multiple of 4; halo only at t0==0
  const int d0 = dg*8;

  // load 7 input row-slices t0-3 .. t0+3
  uint4 w[7];
  const uint4 z4 = make_uint4(0,0,0,0);
  #pragma unroll
  for (int i=0;i<7;i++){
    int off = i - 3;                         // -3..3
    if (t0 == 0 && i < 3) w[i] = z4;
    else w[i] = *(const uint4*)(xi + (size_t)(r0+off)*256 + d0);
  }
  float f[7][8];
  #pragma unroll
  for (int i=0;i<7;i++){
    unsigned int ww[4] = {w[i].x, w[i].y, w[i].z, w[i].w};
    #pragma unroll
    for (int p=0;p<4;p++){
      f[i][p*2+0] = uphalf((unsigned short)(ww[p] & 0xffffu));
      f[i][p*2+1] = uphalf((unsigned short)(ww[p] >> 16));
    }
  }
  // weights: 8 channels x 4 taps, bias 8
  float wt[8][4], bias[8];
  #pragma unroll
  for (int c2=0;c2<2;c2++){
    float4 b4 = *(const float4*)(cb + d0 + c2*4);
    bias[c2*4+0]=b4.x; bias[c2*4+1]=b4.y; bias[c2*4+2]=b4.z; bias[c2*4+3]=b4.w;
  }
  #pragma unroll
  for (int c=0;c<8;c++){
    float4 w4 = *(const float4*)(cw + (d0+c)*4);
    wt[c][0]=w4.x; wt[c][1]=w4.y; wt[c][2]=w4.z; wt[c][3]=w4.w;
  }
  #pragma unroll
  for (int k=0;k<4;k++){
    unsigned int owords[4];
    #pragma unroll
    for (int p=0;p<4;p++){
      float o2[2];
      #pragma unroll
      for (int h=0;h<2;h++){
        int c = p*2+h;
        float acc = bias[c];
        #pragma unroll
        for (int j=0;j<4;j++) acc = fmaf(wt[c][j], f[k+j][c], acc);
        float sig = 1.f/(1.f + __expf(-acc));
        o2[h] = acc*sig;
      }
      owords[p] = pk2(o2[0], o2[1]);
    }
    uint4 outv = make_uint4(owords[0],owords[1],owords[2],owords[3]);
    *(uint4*)(xc + (size_t)(r0+k)*256 + d0) = outv;
  }
}

// -- gemm_x+dt (MFMA): xdbl = xc@Wx; BC[row][32]=B|C; dtb=softplus(dbl@Wdt+b)
__global__ __launch_bounds__(256) void k_gemm_x_dt_mfma(const bf16* __restrict__ xc,
      const bf16* __restrict__ Wxt, const float* __restrict__ Wdt, const float* __restrict__ bdt,
      float* __restrict__ BC, bf16* __restrict__ dtb){
  __shared__ __align__(16) unsigned short a_sh[64][136];
  __shared__ __align__(16) unsigned short b_sh[48][136];
  __shared__ float s_dbl[64][8];
  const int r0 = blockIdx.x*64;              // 1344 blocks
  const int tid = threadIdx.x;
  const int lane = tid & 63, wv = tid >> 6;
  const int fr = lane & 15, fk = (lane>>4)*8;
  const f32x4 zero = {0.f,0.f,0.f,0.f};
  f32x4 acc[3] = {zero,zero,zero};

  for (int kst=0;kst<2;kst++){
    if (kst) __syncthreads();
    #pragma unroll
    for (int q=0;q<4;q++){
      int fid = tid + 256*q;
      int r = fid >> 4, g = fid & 15;
      *(uint4*)&a_sh[r][g*8] = *(const uint4*)(xc + (size_t)(r0+r)*256 + kst*128 + g*8);
      if (fid < 768)
        *(uint4*)&b_sh[r][g*8] = *(const uint4*)(Wxt + (size_t)r*256 + kst*128 + g*8);
    }
    __syncthreads();
    #pragma unroll
    for (int ks=0;ks<4;ks++){
      bf16x8 a0 = *(const bf16x8*)&a_sh[wv*16+fr][ks*32+fk];
      #pragma unroll
      for (int fj=0;fj<3;fj++){
        bf16x8 bb = *(const bf16x8*)&b_sh[fj*16+fr][ks*32+fk];
        acc[fj] = MFMA16(a0,bb,acc[fj]);
      }
    }
  }
  #pragma unroll
  for (int fj=0;fj<3;fj++){
    int col = fj*16 + fr;
    #pragma unroll
    for (int r=0;r<4;r++){
      int rr = wv*16 + (lane>>4)*4 + r;
      size_t row = (size_t)(r0 + rr);
      if (col < 8)       s_dbl[rr][col] = acc[fj][r];
      else if (col < 40) BC[row*32 + (col-8)] = acc[fj][r];
    }
  }
  __syncthreads();
  float wdt[8];
  #pragma unroll
  for (int j=0;j<8;j++) wdt[j] = Wdt[j*256 + tid];
  float bd = bdt[tid];
  #pragma unroll
  for (int r=0;r<64;r++){
    float v = bd;
    #pragma unroll
    for (int j=0;j<8;j++) v = fmaf(s_dbl[r][j], wdt[j], v);
    float sp = (v > 20.f) ? v : log1pf(__expf(v));
    dtb[(size_t)(r0+r)*256 + tid] = f2bf(sp);
  }
}

// ============ chunked selective scan: exact two-pass decomposition ==========
__global__ __launch_bounds__(256) void k_scan_p1(const bf16* __restrict__ xc,
      const bf16* __restrict__ dtb, const float* __restrict__ BC,
      const float* __restrict__ Alog,
      float* __restrict__ hend, float* __restrict__ sumdt, int nc, int cl){
  const int blk = blockIdx.x;
  const int b = blk / nc;
  const int c = blk - b*nc;
  const int d = threadIdx.x;
  float An[16];
  {
    const float4* ap = reinterpret_cast<const float4*>(Alog + d*16);
    float4 a0=ap[0], a1=ap[1], a2=ap[2], a3=ap[3];
    float tmp[16] = {a0.x,a0.y,a0.z,a0.w, a1.x,a1.y,a1.z,a1.w,
                     a2.x,a2.y,a2.z,a2.w, a3.x,a3.y,a3.z,a3.w};
    #pragma unroll
    for (int n=0;n<16;n++) An[n] = -__expf(tmp[n]);
  }
  float h[16];
  #pragma unroll
  for (int n=0;n<16;n++) h[n]=0.f;
  float sdt = 0.f;
  const size_t rowbase = (size_t)b*S_ + (size_t)c*cl;
  for (int t=0;t<cl;t++){
    size_t row = rowbase + t;
    float dtv = bf2f(dtb[row*256 + d]);
    float u   = bf2f(xc [row*256 + d]);
    float du  = dtv*u;
    sdt += dtv;
    const float4* bp = reinterpret_cast<const float4*>(BC + row*32);
    float4 B0=bp[0], B1=bp[1], B2=bp[2], B3=bp[3];
    float Bv[16] = {B0.x,B0.y,B0.z,B0.w, B1.x,B1.y,B1.z,B1.w,
                    B2.x,B2.y,B2.z,B2.w, B3.x,B3.y,B3.z,B3.w};
    #pragma unroll
    for (int n=0;n<16;n++)
      h[n] = fmaf(__expf(dtv*An[n]), h[n], du*Bv[n]);
  }
  float4* hp = reinterpret_cast<float4*>(hend + ((size_t)blk*256 + d)*16);
  hp[0] = make_float4(h[0],h[1],h[2],h[3]);
  hp[1] = make_float4(h[4],h[5],h[6],h[7]);
  hp[2] = make_float4(h[8],h[9],h[10],h[11]);
  hp[3] = make_float4(h[12],h[13],h[14],h[15]);
  sumdt[(size_t)blk*256 + d] = sdt;
}

__global__ __launch_bounds__(256) void k_scan_comb(const float* __restrict__ Alog,
      const float* __restrict__ sumdt, float* __restrict__ hend, int nc){
  const int b = blockIdx.x;
  const int d = threadIdx.x;
  float An[16];
  {
    const float4* ap = reinterpret_cast<const float4*>(Alog + d*16);
    float4 a0=ap[0], a1=ap[1], a2=ap[2], a3=ap[3];
    float tmp[16] = {a0.x,a0.y,a0.z,a0.w, a1.x,a1.y,a1.z,a1.w,
                     a2.x,a2.y,a2.z,a2.w, a3.x,a3.y,a3.z,a3.w};
    #pragma unroll
    for (int n=0;n<16;n++) An[n] = -__expf(tmp[n]);
  }
  float carry[16];
  #pragma unroll
  for (int n=0;n<16;n++) carry[n]=0.f;
  for (int c=0;c<nc;c++){
    size_t blk = (size_t)b*nc + c;
    float4* hp = reinterpret_cast<float4*>(hend + (blk*256 + d)*16);
    float4 e0=hp[0], e1=hp[1], e2=hp[2], e3=hp[3];
    float sdt = sumdt[blk*256 + d];
    hp[0]=make_float4(carry[0],carry[1],carry[2],carry[3]);
    hp[1]=make_float4(carry[4],carry[5],carry[6],carry[7]);
    hp[2]=make_float4(carry[8],carry[9],carry[10],carry[11]);
    hp[3]=make_float4(carry[12],carry[13],carry[14],carry[15]);
    float he[16] = {e0.x,e0.y,e0.z,e0.w, e1.x,e1.y,e1.z,e1.w,
                    e2.x,e2.y,e2.z,e2.w, e3.x,e3.y,e3.z,e3.w};
    #pragma unroll
    for (int n=0;n<16;n++)
      carry[n] = fmaf(__expf(sdt*An[n]), carry[n], he[n]);
  }
}

__global__ __launch_bounds__(256) void k_scan_p2(const bf16* __restrict__ xcin,
      const bf16* __restrict__ dtb, const float* __restrict__ BC,
      const bf16* __restrict__ zb, const float* __restrict__ Alog,
      const float* __restrict__ Dpar, const float* __restrict__ hend,
      bf16* __restrict__ ym, int nc, int cl){
  const int blk = blockIdx.x;
  const int b = blk / nc;
  const int c = blk - b*nc;
  const int d = threadIdx.x;
  float An[16];
  {
    const float4* ap = reinterpret_cast<const float4*>(Alog + d*16);
    float4 a0=ap[0], a1=ap[1], a2=ap[2], a3=ap[3];
    float tmp[16] = {a0.x,a0.y,a0.z,a0.w, a1.x,a1.y,a1.z,a1.w,
                     a2.x,a2.y,a2.z,a2.w, a3.x,a3.y,a3.z,a3.w};
    #pragma unroll
    for (int n=0;n<16;n++) An[n] = -__expf(tmp[n]);
  }
  const float Dpv = Dpar[d];
  float h[16];
  {
    const float4* hp = reinterpret_cast<const float4*>(hend + ((size_t)blk*256 + d)*16);
    float4 h0=hp[0], h1=hp[1], h2=hp[2], h3=hp[3];
    h[0]=h0.x; h[1]=h0.y; h[2]=h0.z; h[3]=h0.w;
    h[4]=h1.x; h[5]=h1.y; h[6]=h1.z; h[7]=h1.w;
    h[8]=h2.x; h[9]=h2.y; h[10]=h2.z; h[11]=h2.w;
    h[12]=h3.x; h[13]=h3.y; h[14]=h3.z; h[15]=h3.w;
  }
  const size_t rowbase = (size_t)b*S_ + (size_t)c*cl;
  for (int t=0;t<cl;t++){
    size_t row = rowbase + t;
    float dtv = bf2f(dtb[row*256 + d]);
    float u   = bf2f(xcin[row*256 + d]);
    float du  = dtv*u;
    const float4* bp = reinterpret_cast<const float4*>(BC + row*32);
    float4 B0=bp[0], B1=bp[1], B2=bp[2], B3=bp[3];
    float4 C0=bp[4], C1=bp[5], C2=bp[6], C3=bp[7];
    float Bv[16] = {B0.x,B0.y,B0.z,B0.w, B1.x,B1.y,B1.z,B1.w,
                    B2.x,B2.y,B2.z,B2.w, B3.x,B3.y,B3.z,B3.w};
    float Cv[16] = {C0.x,C0.y,C0.z,C0.w, C1.x,C1.y,C1.z,C1.w,
                    C2.x,C2.y,C2.z,C2.w, C3.x,C3.y,C3.z,C3.w};
    #pragma unroll
    for (int n=0;n<16;n++)
      h[n] = fmaf(__expf(dtv*An[n]), h[n], du*Bv[n]);
    float a0=0.f,a1=0.f,a2=0.f,a3=0.f;
    #pragma unroll
    for (int n=0;n<16;n+=4){
      a0 = fmaf(h[n+0], Cv[n+0], a0);
      a1 = fmaf(h[n+1], Cv[n+1], a1);
      a2 = fmaf(h[n+2], Cv[n+2], a2);
      a3 = fmaf(h[n+3], Cv[n+3], a3);
    }
    float y = fmaf(u, Dpv, (a0+a1)+(a2+a3));
    float zv = bf2f(zb[row*256 + d]);
    float sig = 1.f/(1.f + __expf(-zv));
    ym[row*256 + d] = f2bf(y * zv * sig);
  }
}

// ------- gemm_out (MFMA): dx = ym @ W_out (K=256), fwd/bwd-fold ------------
__global__ __launch_bounds__(256) void k_gemm_out_mfma(const bf16* __restrict__ ym,
      const bf16* __restrict__ Wt, bf16* __restrict__ dx, int rev){
  __shared__ __align__(16) unsigned short a_sh[64][136];
  __shared__ __align__(16) unsigned short b_sh[64][136];
  const int blk = blockIdx.x;                // 1344 * 2
  const int bm = blk >> 1, bn = blk & 1;
  const int r0 = bm*64, n0 = bn*64;
  const int b  = r0 / S_;
  const int t0 = r0 - b*S_;
  const int tid = threadIdx.x;
  const int lane = tid & 63, wv = tid >> 6;
  const int wr = (wv>>1)*32, wc = (wv&1)*32;
  const int fr = lane & 15, fk = (lane>>4)*8;
  const f32x4 zero = {0.f,0.f,0.f,0.f};
  f32x4 acc[2][2] = {{zero,zero},{zero,zero}};

  for (int kst=0;kst<2;kst++){
    if (kst) __syncthreads();
    #pragma unroll
    for (int q=0;q<4;q++){
      int fid = tid + 256*q;
      int r = fid >> 4, g = fid & 15;
      *(uint4*)&a_sh[r][g*8] = *(const uint4*)(ym + (size_t)(r0+r)*256 + kst*128 + g*8);
      *(uint4*)&b_sh[r][g*8] = *(const uint4*)(Wt + (size_t)(n0+r)*256 + kst*128 + g*8);
    }
    __syncthreads();
    #pragma unroll
    for (int ks=0;ks<4;ks++){
      bf16x8 a0 = *(const bf16x8*)&a_sh[wr+fr   ][ks*32+fk];
      bf16x8 a1 = *(const bf16x8*)&a_sh[wr+16+fr][ks*32+fk];
      bf16x8 b0 = *(const bf16x8*)&b_sh[wc+fr   ][ks*32+fk];
      bf16x8 b1 = *(const bf16x8*)&b_sh[wc+16+fr][ks*32+fk];
      acc[0][0] = MFMA16(a0,b0,acc[0][0]);
      acc[0][1] = MFMA16(a0,b1,acc[0][1]);
      acc[1][0] = MFMA16(a1,b0,acc[1][0]);
      acc[1][1] = MFMA16(a1,b1,acc[1][1]);
    }
  }
  #pragma unroll
  for (int fi=0;fi<2;fi++){
    #pragma unroll
    for (int fj=0;fj<2;fj++){
      int c = n0 + wc + fj*16 + fr;
      #pragma unroll
      for (int r=0;r<4;r++){
        int t = t0 + wr + fi*16 + (lane>>4)*4 + r;
        size_t drow = (size_t)b*S_ + (rev ? (S_-1 - t) : t);
        if (rev){
          float old = bf2f(dx[drow*128 + c]);
          dx[drow*128 + c] = f2bf(old + 0.5f*acc[fi][fj][r]);
        } else {
          dx[drow*128 + c] = f2bf(0.5f*acc[fi][fj][r]);
        }
      }
    }
  }
}

// --- combine + layernorm + residual (vectorized: 4 ch/lane, 2 rows/wave) ---
__global__ __launch_bounds__(256) void k_combine_ln(const bf16* __restrict__ dx,
      const float* __restrict__ lnw, const float* __restrict__ lnb,
      float* __restrict__ x){
  const int tid  = threadIdx.x;
  const int wv   = tid >> 6;
  const int lane = tid & 63;
  const int row  = blockIdx.x*8 + wv*2 + (lane >> 5);
  const int c0   = (lane & 31)*4;
  ushort4 d4 = *(const ushort4*)(dx + (size_t)row*128 + c0);
  float v0 = uphalf(d4.x), v1 = uphalf(d4.y), v2 = uphalf(d4.z), v3 = uphalf(d4.w);
  float s = (v0+v1)+(v2+v3);
  #pragma unroll
  for (int m=1;m<32;m<<=1) s += __shfl_xor(s, m);
  float mu = s * (1.f/128.f);
  float e0 = v0-mu, e1 = v1-mu, e2 = v2-mu, e3 = v3-mu;
  float q = (e0*e0+e1*e1)+(e2*e2+e3*e3);
  #pragma unroll
  for (int m=1;m<32;m<<=1) q += __shfl_xor(q, m);
  float rs = rsqrtf(q*(1.f/128.f) + 1e-5f);
  float4 w4 = *(const float4*)(lnw + c0);
  float4 b4 = *(const float4*)(lnb + c0);
  float4 xv = *(float4*)(x + (size_t)row*128 + c0);
  xv.x += e0*rs*w4.x + b4.x;
  xv.y += e1*rs*w4.y + b4.y;
  xv.z += e2*rs*w4.z + b4.z;
  xv.w += e3*rs*w4.w + b4.w;
  *(float4*)(x + (size_t)row*128 + c0) = xv;
}

// ---------------- pyramid gather ----------------
__global__ void k_pyramid(const float* __restrict__ x, float* __restrict__ out){
  int idx = blockIdx.x*256 + threadIdx.x;
  int j = idx & 31;
  int i = (idx >> 5) & 31;
  int c = (idx >> 10) & 127;
  int m = (idx >> 17) & 31;
  int o = idx >> 22;
  int base = o*1344;
  size_t xm = ((size_t)m * S_ + base) * 128 + c;
  float v = x[xm + (size_t)(320 + i*32 + j)*128]
          + x[xm + (size_t)(64 + (i>>1)*16 + (j>>1))*128]
          + x[xm + (size_t)((i>>2)*8 + (j>>2))*128];
  out[idx] = v;
}

extern "C" void kernel_launch(void* const* d_in, const int* in_sizes, int n_in,
                              void* d_out, int out_size, void* d_ws, size_t ws_size,
                              hipStream_t stream){
  const float* f0   = (const float*)d_in[0];
  const float* f1   = (const float*)d_in[1];
  const float* W_in = (const float*)d_in[2];
  const float* cw   = (const float*)d_in[3];
  const float* cb   = (const float*)d_in[4];
  const float* Wx   = (const float*)d_in[5];
  const float* Wdt  = (const float*)d_in[6];
  const float* bdt  = (const float*)d_in[7];
  const float* Alog = (const float*)d_in[8];
  const float* Dpar = (const float*)d_in[9];
  const float* Wout = (const float*)d_in[10];
  const float* lnw  = (const float*)d_in[11];
  const float* lnb  = (const float*)d_in[12];

  const size_t base = 214695936;
  int nc = 0;
  const int cand[5] = {42,21,12,6,2};
  for (int i=0;i<5;i++){
    size_t need = base + (size_t)32*cand[i]*256*16*4;
    if (ws_size >= need){ nc = cand[i]; break; }
  }
  if (nc == 0) return;
  const int cl = S_/nc;

  char* ws = (char*)d_ws;
  float* x      = (float*)(ws + 0);
  bf16*  xi     = (bf16*) (ws + 44040192);
  bf16*  dtb    = (bf16*) (ws + 44040192);
  bf16*  z      = (bf16*) (ws + 88080384);
  bf16*  xc     = (bf16*) (ws + 132120576);
  float* BC     = (float*)(ws + 176160768);
  float* sumdt  = (float*)(ws + 187170816);
  bf16*  Wt_in  = (bf16*) (ws + 188547072);
  bf16*  Wt_out = (bf16*) (ws + 189071360);
  bf16*  Wxt    = (bf16*) (ws + 189333504);
  bf16*  dx     = (bf16*) (ws + 192675840);
  float* hend   = (float*)(ws + 214695936);

  k_init_x<<<43008,256,0,stream>>>(f0, f1, x);
  k_wconv <<<1728,256,0,stream>>>(W_in, Wx, Wout, Wt_in, Wxt, Wt_out);

  for (int l=0;l<2;l++){
    for (int r=0;r<2;r++){
      int lr = l*2 + r;
      const float* Al = Alog + (size_t)lr*256*16;
      k_gemm_in_mfma  <<<1344,256,0,stream>>>(x, Wt_in + (size_t)lr*65536, xi, z, r);
      k_conv_silu     <<<2688,256,0,stream>>>(xi, cw + lr*256*4, cb + lr*256, xc);
      k_gemm_x_dt_mfma<<<1344,256,0,stream>>>(xc, Wxt + (size_t)lr*12288,
                                              Wdt + (size_t)lr*8*256, bdt + lr*256, BC, dtb);
      k_scan_p1  <<<32*nc,256,0,stream>>>(xc, dtb, BC, Al, hend, sumdt, nc, cl);
      k_scan_comb<<<32,256,0,stream>>>(Al, sumdt, hend, nc);
      k_scan_p2  <<<32*nc,256,0,stream>>>(xc, dtb, BC, z, Al, Dpar + lr*256,
                                          hend, xc, nc, cl);
      k_gemm_out_mfma <<<2688,256,0,stream>>>(xc, Wt_out + (size_t)lr*32768, dx, r);
    }
    k_combine_ln<<<10752,256,0,stream>>>(dx, lnw + l*128, lnb + l*128, x);
  }

  k_pyramid<<<32768,256,0,stream>>>(x, (float*)d_out);
}